// Round 8
// baseline (2611.044 us; speedup 1.0000x reference)
//
#include <hip/hip_runtime.h>
#include <cstdint>
#include <cstddef>

// ---------------------------------------------------------------------------
// SelfAttentionTransformer on MI355X (gfx950).
// L=4, D=1024, H=8, HS=128, T=1000, DFF=4096, B=8.
// R7: 256-wide tiles (gemm256: 512 thr, 8 waves, BK=32, 2-barrier dbuf loop)
//     to halve staging bytes; XCD chunk swizzle; K-RoPE moved into mix-K
//     GEMM epilogue (was 8x-redundant in attn staging).
// ---------------------------------------------------------------------------

typedef unsigned short u16;
typedef unsigned int u32;
typedef __attribute__((ext_vector_type(8))) short s16x8;   // 8 bf16 raw bits
typedef __attribute__((ext_vector_type(4))) float f32x4;
typedef __attribute__((ext_vector_type(4))) unsigned short u16x4;

#define DEV static __device__ __forceinline__

DEV float bf2f(u16 u) { union { u32 u; float f; } v; v.u = ((u32)u) << 16; return v.f; }
DEV u16 f2bf(float f) {
  union { float f; u32 u; } v; v.f = f;
  return (u16)((v.u + 0x7fffu + ((v.u >> 16) & 1u)) >> 16);   // RNE
}

#define MFMA(acc_, a_, b_) \
  asm volatile("v_mfma_f32_16x16x32_bf16 %0, %1, %2, %0" : "+v"(acc_) : "v"(a_), "v"(b_))

#define GLD16(g_, l_) \
  __builtin_amdgcn_global_load_lds((const __attribute__((address_space(1))) void*)(g_), \
                                   (__attribute__((address_space(3))) void*)(l_), 16, 0, 0)

static constexpr int T_ = 1000, D_ = 1024, H_ = 8, HS_ = 128, B_ = 8;
static constexpr int BT_ = B_ * T_;   // 8000

// rope on 8 packed bf16 (4 pairs), table base i0 (pair index of element 0).
DEV void rope8(s16x8& v, const float* __restrict__ ct, const float* __restrict__ st,
               int t, int i0) {
  const f32x4 c4 = *(const f32x4*)(ct + t * 64 + i0);
  const f32x4 s4 = *(const f32x4*)(st + t * 64 + i0);
#pragma unroll
  for (int p = 0; p < 4; ++p) {
    const float xr = bf2f((u16)v[2 * p]), xi = bf2f((u16)v[2 * p + 1]);
    v[2 * p]     = (short)f2bf(xr * c4[p] - xi * s4[p]);
    v[2 * p + 1] = (short)f2bf(xr * s4[p] + xi * c4[p]);
  }
}

// ---------------------------------------------------------------------------
__global__ void tab_kernel(float* __restrict__ ct, float* __restrict__ st) {
  const int id = blockIdx.x * 256 + threadIdx.x;   // 64000
  const int i = id & 63, t = id >> 6;
  const float theta = powf(10000.f, -(float)i * (1.f / 64.f));
  const float ang = (float)t * theta;
  ct[id] = cosf(ang);
  st[id] = sinf(ang);
}

__global__ void convert_kernel(const float* __restrict__ in, u16* __restrict__ out, int n) {
  const int i = (blockIdx.x * 256 + threadIdx.x) * 4;
  if (i < n) {
    const float4 v = *(const float4*)(in + i);
    uint2 pk;
    pk.x = (u32)f2bf(v.x) | ((u32)f2bf(v.y) << 16);
    pk.y = (u32)f2bf(v.z) | ((u32)f2bf(v.w) << 16);
    *(uint2*)(out + i) = pk;
  }
}

// Zero the t/u in [1000,1024) tails of KTg, VTg, Vmt ([8][1024][1024] each).
__global__ void zerotail_kernel(u16* __restrict__ KTg, u16* __restrict__ VTg,
                                u16* __restrict__ Vmt) {
  const int id = blockIdx.x * 256 + threadIdx.x;   // 3 * 8192 * 24 = 589824
  if (id >= 3 * 8192 * 24) return;
  const int which = id / 196608, rem = id % 196608;
  const int bd = rem / 24, t = 1000 + rem % 24;
  u16* p = (which == 0) ? KTg : (which == 1) ? VTg : Vmt;
  p[(size_t)bd * 1024 + t] = 0;
}

// ---------------------------------------------------------------------------
// gemm256: 256-col tile NT GEMM, BM = BMT*128. 512 threads (8 waves, 2Mx4N),
// BK=32, double-buffered LDS, 2-barrier loop (same schedule as proven gemm2p,
// only tile geometry changed). Optional XCD chunk swizzle (cx==0 disables).
// SPLIT: QKV mode (cols<1024 -> Q; [1024,2048) -> KT^T; [2048,3072) -> VT^T).
// Output always bf16. Requires K%32==0, N%256==0. M tail via clamp+guard.
// ---------------------------------------------------------------------------
template <int BMT, int BIAS, bool ACT, bool SPLIT>   // BIAS: 0 none, 2 col
__global__ __launch_bounds__(512) void gemm256(
    const u16* __restrict__ A, const u16* __restrict__ B, u16* __restrict__ Cv,
    const float* __restrict__ bias, u16* __restrict__ KT, u16* __restrict__ VT,
    int M, int N, int K, int lda, int ldb, int ldc, int cx, int cy, int ncx) {
  constexpr int MI = 4 * BMT;
  __shared__ alignas(16) u16 As[2][BMT * 4096];
  __shared__ alignas(16) u16 Bs[2][8192];
  int bx = blockIdx.x, by = blockIdx.y;
  if (cx) {   // XCD chunking: XCD k gets a cx*cy contiguous 2D chunk
    const int lin = by * gridDim.x + bx;
    const int xcd = lin & 7, c2 = lin >> 3;
    bx = (xcd % ncx) * cx + c2 % cx;
    by = (xcd / ncx) * cy + c2 / cx;
  }
  const int m0 = by * (BMT * 128), n0 = bx * 256;
  const int tid = threadIdx.x;
  const int wid = tid >> 6, lane = tid & 63;
  const int wr = wid >> 2, wc = wid & 3;     // 2 x 4 wave grid
  const int l15 = lane & 15, l4 = lane >> 4;
  const int srow = tid >> 2;
  const int sg = ((tid & 3) ^ ((tid >> 3) & 3)) << 3;
  const u16* gA[BMT];
#pragma unroll
  for (int j = 0; j < BMT; ++j)
    gA[j] = A + (size_t)min(m0 + j * 128 + srow, M - 1) * lda + sg;
  const u16* gB0 = B + (size_t)min(n0 + srow, N - 1) * ldb + sg;
  const u16* gB1 = B + (size_t)min(n0 + 128 + srow, N - 1) * ldb + sg;
  const int gg = (l4 ^ ((l15 >> 1) & 3)) << 3;
  const int aBase = (wr * (BMT * 64) + l15) * 32 + gg;
  const int bBase = (wc * 64 + l15) * 32 + gg;

  f32x4 acc[MI][4] = {};
  const int KTn = K >> 5;
#pragma unroll
  for (int j = 0; j < BMT; ++j) GLD16(gA[j], &As[0][j * 4096 + tid * 8]);
  GLD16(gB0, &Bs[0][tid * 8]);
  GLD16(gB1, &Bs[0][4096 + tid * 8]);
  __syncthreads();
  int cur = 0;
#pragma unroll 1
  for (int kt = 0; kt < KTn; ++kt) {
    if (kt + 1 < KTn) {
      const int kb = (kt + 1) << 5;
#pragma unroll
      for (int j = 0; j < BMT; ++j) GLD16(gA[j] + kb, &As[cur ^ 1][j * 4096 + tid * 8]);
      GLD16(gB0 + kb, &Bs[cur ^ 1][tid * 8]);
      GLD16(gB1 + kb, &Bs[cur ^ 1][4096 + tid * 8]);
    }
    s16x8 af[MI], bfr[4];
#pragma unroll
    for (int i = 0; i < MI; ++i) af[i] = *(const s16x8*)&As[cur][aBase + i * 512];
#pragma unroll
    for (int i = 0; i < 4; ++i) bfr[i] = *(const s16x8*)&Bs[cur][bBase + i * 512];
    __builtin_amdgcn_s_setprio(1);
#pragma unroll
    for (int mi = 0; mi < MI; ++mi)
#pragma unroll
      for (int ni = 0; ni < 4; ++ni) MFMA(acc[mi][ni], af[mi], bfr[ni]);
    __builtin_amdgcn_s_setprio(0);
    __syncthreads();
    cur ^= 1;
  }
  asm volatile("s_nop 7\n\ts_nop 7"
               : "+v"(acc[MI - 1][0]), "+v"(acc[MI - 1][1]),
                 "+v"(acc[MI - 1][2]), "+v"(acc[MI - 1][3]));
  if constexpr (SPLIT) {
#pragma unroll
    for (int mi = 0; mi < MI; ++mi) {
      const int rb = m0 + wr * (BMT * 64) + mi * 16 + l4 * 4;   // multiple of 4
      if (rb < M) {
#pragma unroll
        for (int ni = 0; ni < 4; ++ni) {
          const int colg = n0 + wc * 64 + ni * 16 + l15;
          if (colg < 1024) {
#pragma unroll
            for (int r = 0; r < 4; ++r)
              Cv[(size_t)(rb + r) * 1024 + colg] = f2bf(acc[mi][ni][r]);
          } else {
            u16* dst = (colg < 2048) ? KT : VT;
            const int dcol = colg & 1023;
            const int bq = rb / 1000;
            const int tq = rb - bq * 1000;
            u16x4 pk;
#pragma unroll
            for (int r = 0; r < 4; ++r) pk[r] = f2bf(acc[mi][ni][r]);
            *(u16x4*)(dst + (size_t)bq * 1048576 + (size_t)dcol * 1024 + tq) = pk;
          }
        }
      }
    }
  } else {
#pragma unroll
    for (int mi = 0; mi < MI; ++mi) {
#pragma unroll
      for (int ni = 0; ni < 4; ++ni) {
        const int colg = n0 + wc * 64 + ni * 16 + l15;
#pragma unroll
        for (int r = 0; r < 4; ++r) {
          const int rowg = m0 + wr * (BMT * 64) + mi * 16 + l4 * 4 + r;
          if (rowg < M) {
            float v = acc[mi][ni][r];
            if (BIAS == 2) v += bias[colg];
            if (ACT) v = 0.5f * v * (1.0f + erff(v * 0.70710678118654752f));
            Cv[(size_t)rowg * ldc + colg] = f2bf(v);
          }
        }
      }
    }
  }
}

// ---------------------------------------------------------------------------
// gemm2p (proven 128x128): used for the two position-mix GEMMs.
// RK: fuse K-RoPE into the epilogue (t = row u, pairs along d via shfl_xor).
// ---------------------------------------------------------------------------
template <int BIAS, bool ACT, bool OUTBF, bool RK>   // BIAS: 0 none,1 row,2 col
__global__ __launch_bounds__(256) void gemm2p(
    const u16* __restrict__ A, const u16* __restrict__ B, void* __restrict__ Cv,
    const float* __restrict__ bias, const float* __restrict__ ct,
    const float* __restrict__ st, int M, int N, int K, int lda, int ldb, int ldc,
    long sA, long sB, long sC) {
  __shared__ alignas(16) u16 As[2][4096];
  __shared__ alignas(16) u16 Bs[2][4096];
  const int z = blockIdx.z;
  A += (size_t)z * (size_t)sA;
  B += (size_t)z * (size_t)sB;
  const int m0 = blockIdx.y * 128, n0 = blockIdx.x * 128;
  const int tid = threadIdx.x;
  const int wid = tid >> 6, lane = tid & 63;
  const int wr = wid >> 1, wc = wid & 1;
  const int l15 = lane & 15, l4 = lane >> 4;
  const int srow = tid >> 2;
  const int sg = ((tid & 3) ^ ((tid >> 3) & 3)) << 3;
  const u16* gA0 = A + (size_t)min(m0 + srow, M - 1) * lda + sg;
  const u16* gA1 = A + (size_t)min(m0 + 64 + srow, M - 1) * lda + sg;
  const u16* gB0 = B + (size_t)min(n0 + srow, N - 1) * ldb + sg;
  const u16* gB1 = B + (size_t)min(n0 + 64 + srow, N - 1) * ldb + sg;
  const int gg = (l4 ^ ((l15 >> 1) & 3)) << 3;
  const int aBase = (wr * 64 + l15) * 32 + gg;
  const int bBase = (wc * 64 + l15) * 32 + gg;

  f32x4 acc[4][4] = {};
  const int KTn = K >> 5;
  GLD16(gA0, &As[0][tid * 8]);
  GLD16(gA1, &As[0][(256 + tid) * 8]);
  GLD16(gB0, &Bs[0][tid * 8]);
  GLD16(gB1, &Bs[0][(256 + tid) * 8]);
  __syncthreads();
  int cur = 0;
#pragma unroll 1
  for (int kt = 0; kt < KTn; ++kt) {
    if (kt + 1 < KTn) {
      const int kb = (kt + 1) << 5;
      GLD16(gA0 + kb, &As[cur ^ 1][tid * 8]);
      GLD16(gA1 + kb, &As[cur ^ 1][(256 + tid) * 8]);
      GLD16(gB0 + kb, &Bs[cur ^ 1][tid * 8]);
      GLD16(gB1 + kb, &Bs[cur ^ 1][(256 + tid) * 8]);
    }
    s16x8 af[4], bfr[4];
#pragma unroll
    for (int i = 0; i < 4; ++i) af[i] = *(const s16x8*)&As[cur][aBase + i * 512];
#pragma unroll
    for (int i = 0; i < 4; ++i) bfr[i] = *(const s16x8*)&Bs[cur][bBase + i * 512];
    __builtin_amdgcn_s_setprio(1);
#pragma unroll
    for (int mi = 0; mi < 4; ++mi)
#pragma unroll
      for (int ni = 0; ni < 4; ++ni) MFMA(acc[mi][ni], af[mi], bfr[ni]);
    __builtin_amdgcn_s_setprio(0);
    __syncthreads();
    cur ^= 1;
  }
  asm volatile("s_nop 7\n\ts_nop 7"
               : "+v"(acc[3][0]), "+v"(acc[3][1]), "+v"(acc[3][2]), "+v"(acc[3][3]));
#pragma unroll
  for (int mi = 0; mi < 4; ++mi) {
#pragma unroll
    for (int ni = 0; ni < 4; ++ni) {
      const int colg = n0 + wc * 64 + ni * 16 + l15;
#pragma unroll
      for (int r = 0; r < 4; ++r) {
        const int rowg = m0 + wr * 64 + mi * 16 + l4 * 4 + r;
        float v = acc[mi][ni][r];
        if (BIAS == 1) v += bias[min(rowg, M - 1)];
        if (BIAS == 2) v += bias[colg];
        if constexpr (RK) {
          // K rope: t = rowg (position u), pair along d: partner lane l15^1.
          const int tt = min(rowg, T_ - 1);
          const int ii = (colg & 127) >> 1;
          const float c = ct[tt * 64 + ii], s = st[tt * 64 + ii];
          const float partner = __shfl_xor(v, 1);
          v = (colg & 1) ? (partner * s + v * c) : (v * c - partner * s);
        }
        if (ACT) v = 0.5f * v * (1.0f + erff(v * 0.70710678118654752f));
        if (rowg < M && colg < N) {
          const size_t idx = (size_t)z * (size_t)sC + (size_t)rowg * ldc + colg;
          if (OUTBF) ((u16*)Cv)[idx] = f2bf(v);
          else       ((float*)Cv)[idx] = v;
        }
      }
    }
  }
}

// ---------------------------------------------------------------------------
// Flash attention (non-causal), QBLK=128 (4 waves x 32 q-rows), KVBLK=64.
// Q-RoPE fused at fragment load; K arrives pre-roped (mix epilogue).
// ---------------------------------------------------------------------------
__global__ __launch_bounds__(256) void attn_kernel(const u16* __restrict__ Q,
                                                   const u16* __restrict__ Km,
                                                   const u16* __restrict__ Vmt,
                                                   u16* __restrict__ Y,
                                                   const float* __restrict__ ct,
                                                   const float* __restrict__ st) {
  __shared__ alignas(16) u16 Ks[64][136];
  __shared__ alignas(16) u16 Vts[128][72];
  __shared__ alignas(16) u16 Ps[4][32][72];
  const int qt = blockIdx.x;
  const int bh = blockIdx.y;
  const int b = bh >> 3, h = bh & 7;
  const int tid = threadIdx.x;
  const int w = tid >> 6, lane = tid & 63;
  const int l15 = lane & 15, l4 = lane >> 4;
  const size_t qbase = (size_t)b * 1000 * 1024 + h * HS_;
  const size_t kbase = (size_t)b * 1024000 + h * HS_;
  const size_t vbase = (size_t)b * 1048576 + (size_t)(h * HS_) * 1024;
  const int q0 = qt * 128 + w * 32;
  s16x8 aq[2][4];
#pragma unroll
  for (int qf = 0; qf < 2; ++qf) {
    const int qrow = q0 + qf * 16 + l15;
#pragma unroll
    for (int c = 0; c < 4; ++c) {
      s16x8 v = {};
      if (qrow < T_) {
        v = *(const s16x8*)(Q + qbase + (size_t)qrow * 1024 + c * 32 + l4 * 8);
        rope8(v, ct, st, qrow, c * 16 + l4 * 4);
      }
      aq[qf][c] = v;
    }
  }
  f32x4 acc[2][8] = {};
  float m_run[2][4], l_run[2][4];
#pragma unroll
  for (int qf = 0; qf < 2; ++qf)
#pragma unroll
    for (int r = 0; r < 4; ++r) { m_run[qf][r] = -1e30f; l_run[qf][r] = 0.f; }
  const float SCALE = 0.08838834764831845f;
  for (int kt = 0; kt < 16; ++kt) {
    {
      const int r = tid >> 2, c0 = (tid & 3) << 5;
      const int kk = kt * 64 + r;
#pragma unroll
      for (int v = 0; v < 4; ++v) {
        s16x8 val = {};
        if (kk < T_) val = *(const s16x8*)(Km + kbase + (size_t)kk * 1024 + c0 + v * 8);
        *(s16x8*)&Ks[r][c0 + v * 8] = val;
      }
      const int r2 = tid >> 1, c2s = (tid & 1) << 5;
#pragma unroll
      for (int v = 0; v < 4; ++v) {
        const s16x8 val = *(const s16x8*)(Vmt + vbase + (size_t)r2 * 1024 + kt * 64 + c2s + v * 8);
        *(s16x8*)&Vts[r2][c2s + v * 8] = val;
      }
    }
    __syncthreads();
    f32x4 sacc[2][4] = {};
#pragma unroll
    for (int c = 0; c < 4; ++c) {
      s16x8 bk[4];
#pragma unroll
      for (int f = 0; f < 4; ++f) bk[f] = *(const s16x8*)&Ks[f * 16 + l15][c * 32 + l4 * 8];
#pragma unroll
      for (int qf = 0; qf < 2; ++qf)
#pragma unroll
        for (int f = 0; f < 4; ++f) MFMA(sacc[qf][f], aq[qf][c], bk[f]);
    }
    asm volatile("s_nop 7\n\ts_nop 7"
                 : "+v"(sacc[0][0]), "+v"(sacc[0][1]), "+v"(sacc[0][2]), "+v"(sacc[0][3]),
                   "+v"(sacc[1][0]), "+v"(sacc[1][1]), "+v"(sacc[1][2]), "+v"(sacc[1][3]));
#pragma unroll
    for (int qf = 0; qf < 2; ++qf) {
      float sv[4][4];
#pragma unroll
      for (int f = 0; f < 4; ++f) {
        const int key = kt * 64 + f * 16 + l15;
#pragma unroll
        for (int r = 0; r < 4; ++r) sv[f][r] = (key < T_) ? sacc[qf][f][r] * SCALE : -1e30f;
      }
#pragma unroll
      for (int r = 0; r < 4; ++r) {
        float mx = fmaxf(fmaxf(sv[0][r], sv[1][r]), fmaxf(sv[2][r], sv[3][r]));
#pragma unroll
        for (int off = 8; off >= 1; off >>= 1) mx = fmaxf(mx, __shfl_xor(mx, off));
        const float mn = fmaxf(m_run[qf][r], mx);
        const float corr = __expf(m_run[qf][r] - mn);
        m_run[qf][r] = mn;
        float rs = 0.f;
#pragma unroll
        for (int f = 0; f < 4; ++f) {
          const float p = __expf(sv[f][r] - mn);
          rs += p;
          Ps[w][qf * 16 + l4 * 4 + r][f * 16 + l15] = f2bf(p);
        }
#pragma unroll
        for (int off = 8; off >= 1; off >>= 1) rs += __shfl_xor(rs, off);
        l_run[qf][r] = l_run[qf][r] * corr + rs;
#pragma unroll
        for (int n = 0; n < 8; ++n) acc[qf][n][r] *= corr;
      }
    }
    asm volatile("s_waitcnt lgkmcnt(0)" ::: "memory");
#pragma unroll
    for (int c2 = 0; c2 < 2; ++c2) {
      s16x8 pa[2];
#pragma unroll
      for (int qf = 0; qf < 2; ++qf)
        pa[qf] = *(const s16x8*)&Ps[w][qf * 16 + l15][c2 * 32 + l4 * 8];
#pragma unroll
      for (int n = 0; n < 8; ++n) {
        const s16x8 vb = *(const s16x8*)&Vts[n * 16 + l15][c2 * 32 + l4 * 8];
#pragma unroll
        for (int qf = 0; qf < 2; ++qf) MFMA(acc[qf][n], pa[qf], vb);
      }
    }
    __syncthreads();
  }
  asm volatile("s_nop 7\n\ts_nop 7"
               : "+v"(acc[0][6]), "+v"(acc[0][7]), "+v"(acc[1][6]), "+v"(acc[1][7]));
#pragma unroll
  for (int qf = 0; qf < 2; ++qf)
#pragma unroll
    for (int n = 0; n < 8; ++n)
#pragma unroll
      for (int r = 0; r < 4; ++r) {
        const int q = q0 + qf * 16 + l4 * 4 + r;
        if (q < T_)
          Y[(size_t)(b * 1000 + q) * 1024 + h * HS_ + n * 16 + l15] =
              f2bf(acc[qf][n][r] / l_run[qf][r]);
      }
}

// ---------------------------------------------------------------------------
// src = LN(src + bf16 add) * g + b  (fp32 master) + bf16 mirror. Vectorized.
// ---------------------------------------------------------------------------
__global__ __launch_bounds__(256) void addln_kernel(float* __restrict__ src,
                                                    const u16* __restrict__ add,
                                                    const float* __restrict__ g,
                                                    const float* __restrict__ bb,
                                                    u16* __restrict__ outb) {
  const int row = blockIdx.x;
  const int tid = threadIdx.x;
  const int d = tid * 4;
  float* s = src + (size_t)row * D_;
  const u16* a = add + (size_t)row * D_;
  f32x4 sv = *(const f32x4*)(s + d);
  const u16x4 av = *(const u16x4*)(a + d);
  float x[4];
  float sum = 0.f, sq = 0.f;
#pragma unroll
  for (int i = 0; i < 4; ++i) {
    const float v = sv[i] + bf2f(av[i]);
    x[i] = v; sum += v; sq += v * v;
  }
#pragma unroll
  for (int off = 32; off >= 1; off >>= 1) { sum += __shfl_xor(sum, off); sq += __shfl_xor(sq, off); }
  __shared__ float red[8];
  const int wid = tid >> 6;
  if ((tid & 63) == 0) { red[wid] = sum; red[4 + wid] = sq; }
  __syncthreads();
  sum = red[0] + red[1] + red[2] + red[3];
  sq = red[4] + red[5] + red[6] + red[7];
  const float mean = sum * (1.f / 1024.f);
  const float var = sq * (1.f / 1024.f) - mean * mean;
  const float rstd = rsqrtf(var + 1e-5f);
  const f32x4 gv = *(const f32x4*)(g + d);
  const f32x4 bv = *(const f32x4*)(bb + d);
  f32x4 yv;
  u16x4 ob;
#pragma unroll
  for (int i = 0; i < 4; ++i) {
    const float y = (x[i] - mean) * rstd * gv[i] + bv[i];
    yv[i] = y;
    ob[i] = f2bf(y);
  }
  *(f32x4*)(s + d) = yv;
  *(u16x4*)(outb + (size_t)row * D_ + d) = ob;
}

// ---------------------------------------------------------------------------
// Host orchestration
// ---------------------------------------------------------------------------
static inline int cdiv(int a, int b) { return (a + b - 1) / b; }

extern "C" void kernel_launch(void* const* d_in, const int* in_sizes, int n_in,
                              void* d_out, int out_size, void* d_ws, size_t ws_size,
                              hipStream_t stream) {
  const float* x    = (const float*)d_in[0];
  const float* Wq   = (const float*)d_in[1];
  const float* Wk   = (const float*)d_in[2];
  const float* Wv   = (const float*)d_in[3];
  const float* Wpk  = (const float*)d_in[4];
  const float* bpk  = (const float*)d_in[5];
  const float* Wpv  = (const float*)d_in[6];
  const float* bpv  = (const float*)d_in[7];
  const float* g1   = (const float*)d_in[8];
  const float* b1ln = (const float*)d_in[9];
  const float* W1   = (const float*)d_in[10];
  const float* b1   = (const float*)d_in[11];
  const float* W2   = (const float*)d_in[12];
  const float* b2   = (const float*)d_in[13];
  const float* g2   = (const float*)d_in[14];
  const float* b2ln = (const float*)d_in[15];

  char* wsb = (char*)d_ws;
  float* cosT = (float*)(wsb + 0);                //   256 KB
  float* sinT = (float*)(wsb + 262144);           //   256 KB
  float* srcf = (float*)(wsb + 524288);           // 32.77 MB fp32 residual
  u16* srcb   = (u16*)(wsb + 33292288);           // 16.38 MB bf16 mirror
  u16* Qb     = (u16*)(wsb + 49676288);           // 16.38 MB [8000][1024]
  u16* KTg    = (u16*)(wsb + 66060288);           // 16.78 MB [8][1024 d][1024 t]
  u16* VTg    = (u16*)(wsb + 82837504);           // 16.78 MB [8][1024 d][1024 t]
  u16* Km     = (u16*)(wsb + 99614720);           // 16.38 MB [8][1000][1024]
  u16* Vmt    = (u16*)(wsb + 115998720);          // 16.78 MB [8][1024 d][1024 u]
  u16* yB     = (u16*)(wsb + 132775936);          // 16.38 MB [8000][1024] bf16 y
  u16* wbuf   = (u16*)(wsb + 149159936);          // 27.07 MB layer weights
  u16* hB     = Qb;  // [8000][4096] overlaps Qb+KTg+VTg+Km (all dead at FFN time)

  u16* wqB  = wbuf + 0;          // [3072][1024] fused q,k,v
  u16* wpkB = wbuf + 3145728;    // [1000][1000]
  u16* wpvB = wbuf + 4145728;
  u16* w1B  = wbuf + 5145728;    // [4096][1024]
  u16* w2B  = wbuf + 9340032;    // [1024][4096]

  tab_kernel<<<250, 256, 0, stream>>>(cosT, sinT);
  zerotail_kernel<<<2304, 256, 0, stream>>>(KTg, VTg, Vmt);
  hipMemcpyAsync(srcf, x, (size_t)BT_ * D_ * sizeof(float), hipMemcpyDeviceToDevice, stream);
  convert_kernel<<<cdiv(BT_ * D_, 1024), 256, 0, stream>>>(x, srcb, BT_ * D_);

  for (int l = 0; l < 4; ++l) {
    convert_kernel<<<cdiv(1048576, 1024), 256, 0, stream>>>(Wq + (size_t)l * 1048576, wqB, 1048576);
    convert_kernel<<<cdiv(1048576, 1024), 256, 0, stream>>>(Wk + (size_t)l * 1048576, wqB + 1048576, 1048576);
    convert_kernel<<<cdiv(1048576, 1024), 256, 0, stream>>>(Wv + (size_t)l * 1048576, wqB + 2097152, 1048576);
    convert_kernel<<<cdiv(1000000, 1024), 256, 0, stream>>>(Wpk + (size_t)l * 1000000, wpkB, 1000000);
    convert_kernel<<<cdiv(1000000, 1024), 256, 0, stream>>>(Wpv + (size_t)l * 1000000, wpvB, 1000000);
    convert_kernel<<<cdiv(4194304, 1024), 256, 0, stream>>>(W1 + (size_t)l * 4194304, w1B, 4194304);
    convert_kernel<<<cdiv(4194304, 1024), 256, 0, stream>>>(W2 + (size_t)l * 4194304, w2B, 4194304);

    // Fused QKV (split epilogue): grid 12x32, XCD chunks 6x8 (2x4 chunk grid)
    gemm256<2, 0, false, true><<<dim3(12, 32), 512, 0, stream>>>(
        srcb, wqB, Qb, nullptr, KTg, VTg, BT_, 3072, 1024, 1024, 1024, 1024, 6, 8, 2);

    // K position-mix + fused K-RoPE: Km[b][u][d] = rope(sum_t Wpk[u,t] KTg[b][d][t] + bpk[u])
    gemm2p<1, false, true, true><<<dim3(8, 8, 8), 256, 0, stream>>>(
        wpkB, KTg, Km, bpk + (size_t)l * 1000, cosT, sinT,
        1000, 1024, 1024, 1000, 1024, 1024, 0L, 1048576L, 1024000L);

    // V position-mix (transposed out): Vmt[b][d][u] = sum_t VTg[b][d][t] Wpv[u,t] + bpv[u]
    gemm2p<2, false, true, false><<<dim3(8, 8, 8), 256, 0, stream>>>(
        VTg, wpvB, Vmt, bpv + (size_t)l * 1000, nullptr, nullptr,
        1024, 1000, 1024, 1024, 1000, 1024, 1048576L, 0L, 1048576L);

    // Attention (Q-rope fused; K pre-roped), bf16 out
    attn_kernel<<<dim3(8, 64), 256, 0, stream>>>(Qb, Km, Vmt, yB, cosT, sinT);

    addln_kernel<<<BT_, 256, 0, stream>>>(srcf, yB, g1 + (size_t)l * 1024,
                                          b1ln + (size_t)l * 1024, srcb);

    // FFN1 (+bias+gelu): grid 16x32, XCD chunks 8x8 (2x4 chunk grid)
    gemm256<2, 2, true, false><<<dim3(16, 32), 512, 0, stream>>>(
        srcb, w1B, hB, b1 + (size_t)l * 4096, nullptr, nullptr,
        BT_, 4096, 1024, 1024, 1024, 4096, 8, 8, 2);
    // FFN2 (+bias) -> bf16 yB: 128x256 tiles, grid 4x63 (252 blocks, no swizzle)
    gemm256<1, 2, false, false><<<dim3(4, 63), 512, 0, stream>>>(
        hB, w2B, yB, b2 + (size_t)l * 1024, nullptr, nullptr,
        BT_, 1024, 4096, 4096, 4096, 1024, 0, 0, 0);

    addln_kernel<<<BT_, 256, 0, stream>>>(srcf, yB, g2 + (size_t)l * 1024,
                                          b2ln + (size_t)l * 1024, srcb);
  }

  hipMemcpyAsync(d_out, srcf, (size_t)BT_ * D_ * sizeof(float), hipMemcpyDeviceToDevice, stream);
}

// Round 10
// 2110.961 us; speedup vs baseline: 1.2369x; 1.2369x over previous
//
#include <hip/hip_runtime.h>
#include <cstdint>
#include <cstddef>

// ---------------------------------------------------------------------------
// SelfAttentionTransformer on MI355X (gfx950).
// L=4, D=1024, H=8, HS=128, T=1000, DFF=4096, B=8.
// R10: bisect of R9's NaN — attn keeps the MFMA ones-trick row-sum but
//      restores R8's EXACT per-tile rescale (defer-max removed).
//      convertL fusion + clamps + K-RoPE-in-mix retained. gemm2p everywhere.
// ---------------------------------------------------------------------------

typedef unsigned short u16;
typedef unsigned int u32;
typedef __attribute__((ext_vector_type(8))) short s16x8;   // 8 bf16 raw bits
typedef __attribute__((ext_vector_type(4))) float f32x4;
typedef __attribute__((ext_vector_type(4))) unsigned short u16x4;

#define DEV static __device__ __forceinline__

DEV float bf2f(u16 u) { union { u32 u; float f; } v; v.u = ((u32)u) << 16; return v.f; }
DEV u16 f2bf(float f) {
  union { float f; u32 u; } v; v.f = f;
  return (u16)((v.u + 0x7fffu + ((v.u >> 16) & 1u)) >> 16);   // RNE
}

#define MFMA(acc_, a_, b_) \
  asm volatile("v_mfma_f32_16x16x32_bf16 %0, %1, %2, %0" : "+v"(acc_) : "v"(a_), "v"(b_))

#define GLD16(g_, l_) \
  __builtin_amdgcn_global_load_lds((const __attribute__((address_space(1))) void*)(g_), \
                                   (__attribute__((address_space(3))) void*)(l_), 16, 0, 0)

static constexpr int T_ = 1000, D_ = 1024, H_ = 8, HS_ = 128, B_ = 8;
static constexpr int BT_ = B_ * T_;   // 8000

// rope on 8 packed bf16 (4 pairs), table base i0 (pair index of element 0).
DEV void rope8(s16x8& v, const float* __restrict__ ct, const float* __restrict__ st,
               int t, int i0) {
  const f32x4 c4 = *(const f32x4*)(ct + t * 64 + i0);
  const f32x4 s4 = *(const f32x4*)(st + t * 64 + i0);
#pragma unroll
  for (int p = 0; p < 4; ++p) {
    const float xr = bf2f((u16)v[2 * p]), xi = bf2f((u16)v[2 * p + 1]);
    v[2 * p]     = (short)f2bf(xr * c4[p] - xi * s4[p]);
    v[2 * p + 1] = (short)f2bf(xr * s4[p] + xi * c4[p]);
  }
}

// ---------------------------------------------------------------------------
__global__ void tab_kernel(float* __restrict__ ct, float* __restrict__ st) {
  const int id = blockIdx.x * 256 + threadIdx.x;   // 64000
  const int i = id & 63, t = id >> 6;
  const float theta = powf(10000.f, -(float)i * (1.f / 64.f));
  const float ang = (float)t * theta;
  ct[id] = cosf(ang);
  st[id] = sinf(ang);
}

__global__ void convert_kernel(const float* __restrict__ in, u16* __restrict__ out, int n) {
  const int i = (blockIdx.x * 256 + threadIdx.x) * 4;
  if (i < n) {
    const float4 v = *(const float4*)(in + i);
    uint2 pk;
    pk.x = (u32)f2bf(v.x) | ((u32)f2bf(v.y) << 16);
    pk.y = (u32)f2bf(v.z) | ((u32)f2bf(v.w) << 16);
    *(uint2*)(out + i) = pk;
  }
}

// All 7 per-layer weight converts fused (float4 quads, segmented).
__global__ __launch_bounds__(256) void convertL_kernel(
    const float* __restrict__ Wq, const float* __restrict__ Wk, const float* __restrict__ Wv,
    const float* __restrict__ Wpk, const float* __restrict__ Wpv,
    const float* __restrict__ W1, const float* __restrict__ W2,
    u16* __restrict__ wq, u16* __restrict__ wpk, u16* __restrict__ wpv,
    u16* __restrict__ w1, u16* __restrict__ w2) {
  const int i = blockIdx.x * 256 + threadIdx.x;
  const float* src; u16* dst; int j;
  if      (i <  262144) { src = Wq;  dst = wq;            j = i; }
  else if (i <  524288) { src = Wk;  dst = wq + 1048576;  j = i -  262144; }
  else if (i <  786432) { src = Wv;  dst = wq + 2097152;  j = i -  524288; }
  else if (i < 1036432) { src = Wpk; dst = wpk;           j = i -  786432; }
  else if (i < 1286432) { src = Wpv; dst = wpv;           j = i - 1036432; }
  else if (i < 2335008) { src = W1;  dst = w1;            j = i - 1286432; }
  else if (i < 3383584) { src = W2;  dst = w2;            j = i - 2335008; }
  else return;
  const float4 v = ((const float4*)src)[j];
  uint2 pk;
  pk.x = (u32)f2bf(v.x) | ((u32)f2bf(v.y) << 16);
  pk.y = (u32)f2bf(v.z) | ((u32)f2bf(v.w) << 16);
  ((uint2*)dst)[j] = pk;
}

// Zero the t/u in [1000,1024) tails of KTg, VTg, Vmt ([8][1024][1024] each).
__global__ void zerotail_kernel(u16* __restrict__ KTg, u16* __restrict__ VTg,
                                u16* __restrict__ Vmt) {
  const int id = blockIdx.x * 256 + threadIdx.x;   // 3 * 8192 * 24 = 589824
  if (id >= 3 * 8192 * 24) return;
  const int which = id / 196608, rem = id % 196608;
  const int bd = rem / 24, t = 1000 + rem % 24;
  u16* p = (which == 0) ? KTg : (which == 1) ? VTg : Vmt;
  p[(size_t)bd * 1024 + t] = 0;
}

// ---------------------------------------------------------------------------
// gemm2p: proven 128x128 / BK=32 / 256-thread / double-buffered NT GEMM.
// RK: fuse K-RoPE into epilogue (t = row u, pairs along d via shfl_xor).
// SPLIT: QKV mode — cols<1024 -> Cv(Q); [1024,2048) -> KT^T; [2048,3072) -> VT^T.
// Output bf16. Requires K%32==0. M/N tails via clamp + store guard.
// ---------------------------------------------------------------------------
template <int BIAS, bool ACT, bool RK, bool SPLIT>   // BIAS: 0 none, 1 row, 2 col
__global__ __launch_bounds__(256) void gemm2p(
    const u16* __restrict__ A, const u16* __restrict__ B, u16* __restrict__ Cv,
    const float* __restrict__ bias, const float* __restrict__ ct,
    const float* __restrict__ st, u16* __restrict__ KT, u16* __restrict__ VT,
    int M, int N, int K, int lda, int ldb, int ldc, long sA, long sB, long sC) {
  __shared__ alignas(16) u16 As[2][4096];
  __shared__ alignas(16) u16 Bs[2][4096];
  const int z = blockIdx.z;
  A += (size_t)z * (size_t)sA;
  B += (size_t)z * (size_t)sB;
  const int m0 = blockIdx.y * 128, n0 = blockIdx.x * 128;
  const int tid = threadIdx.x;
  const int wid = tid >> 6, lane = tid & 63;
  const int wr = wid >> 1, wc = wid & 1;
  const int l15 = lane & 15, l4 = lane >> 4;
  const int srow = tid >> 2;
  const int sg = ((tid & 3) ^ ((tid >> 3) & 3)) << 3;
  const u16* gA0 = A + (size_t)min(m0 + srow, M - 1) * lda + sg;
  const u16* gA1 = A + (size_t)min(m0 + 64 + srow, M - 1) * lda + sg;
  const u16* gB0 = B + (size_t)min(n0 + srow, N - 1) * ldb + sg;
  const u16* gB1 = B + (size_t)min(n0 + 64 + srow, N - 1) * ldb + sg;
  const int gg = (l4 ^ ((l15 >> 1) & 3)) << 3;
  const int aBase = (wr * 64 + l15) * 32 + gg;
  const int bBase = (wc * 64 + l15) * 32 + gg;

  f32x4 acc[4][4] = {};
  const int KTn = K >> 5;
  GLD16(gA0, &As[0][tid * 8]);
  GLD16(gA1, &As[0][(256 + tid) * 8]);
  GLD16(gB0, &Bs[0][tid * 8]);
  GLD16(gB1, &Bs[0][(256 + tid) * 8]);
  __syncthreads();
  int cur = 0;
#pragma unroll 1
  for (int kt = 0; kt < KTn; ++kt) {
    if (kt + 1 < KTn) {
      const int kb = (kt + 1) << 5;
      GLD16(gA0 + kb, &As[cur ^ 1][tid * 8]);
      GLD16(gA1 + kb, &As[cur ^ 1][(256 + tid) * 8]);
      GLD16(gB0 + kb, &Bs[cur ^ 1][tid * 8]);
      GLD16(gB1 + kb, &Bs[cur ^ 1][(256 + tid) * 8]);
    }
    s16x8 af[4], bfr[4];
#pragma unroll
    for (int i = 0; i < 4; ++i) af[i] = *(const s16x8*)&As[cur][aBase + i * 512];
#pragma unroll
    for (int i = 0; i < 4; ++i) bfr[i] = *(const s16x8*)&Bs[cur][bBase + i * 512];
    __builtin_amdgcn_s_setprio(1);
#pragma unroll
    for (int mi = 0; mi < 4; ++mi)
#pragma unroll
      for (int ni = 0; ni < 4; ++ni) MFMA(acc[mi][ni], af[mi], bfr[ni]);
    __builtin_amdgcn_s_setprio(0);
    __syncthreads();
    cur ^= 1;
  }
  asm volatile("s_nop 7\n\ts_nop 7"
               : "+v"(acc[3][0]), "+v"(acc[3][1]), "+v"(acc[3][2]), "+v"(acc[3][3]));
  if constexpr (SPLIT) {
#pragma unroll
    for (int mi = 0; mi < 4; ++mi) {
      const int rb = m0 + wr * 64 + mi * 16 + l4 * 4;   // multiple of 4
      if (rb < M) {
#pragma unroll
        for (int ni = 0; ni < 4; ++ni) {
          const int colg = n0 + wc * 64 + ni * 16 + l15;
          if (colg < 1024) {
#pragma unroll
            for (int r = 0; r < 4; ++r)
              Cv[(size_t)(rb + r) * 1024 + colg] = f2bf(acc[mi][ni][r]);
          } else {
            u16* dst = (colg < 2048) ? KT : VT;
            const int dcol = colg & 1023;
            const int bq = rb / 1000;
            const int tq = rb - bq * 1000;   // mult of 4, <=996: no straddle
            u16x4 pk;
#pragma unroll
            for (int r = 0; r < 4; ++r) pk[r] = f2bf(acc[mi][ni][r]);
            *(u16x4*)(dst + (size_t)bq * 1048576 + (size_t)dcol * 1024 + tq) = pk;
          }
        }
      }
    }
  } else {
#pragma unroll
    for (int mi = 0; mi < 4; ++mi) {
#pragma unroll
      for (int ni = 0; ni < 4; ++ni) {
        const int colg = n0 + wc * 64 + ni * 16 + l15;
#pragma unroll
        for (int r = 0; r < 4; ++r) {
          const int rowg = m0 + wr * 64 + mi * 16 + l4 * 4 + r;
          float v = acc[mi][ni][r];
          if (BIAS == 1) v += bias[min(rowg, M - 1)];
          if (BIAS == 2) v += bias[min(colg, N - 1)];
          if constexpr (RK) {
            // K rope: t = rowg (position u), pair along d: partner lane l15^1.
            const int tt = min(rowg, T_ - 1);
            const int ii = (colg & 127) >> 1;
            const float c = ct[tt * 64 + ii], s = st[tt * 64 + ii];
            const float partner = __shfl_xor(v, 1);
            v = (colg & 1) ? (partner * s + v * c) : (v * c - partner * s);
          }
          if (ACT) v = 0.5f * v * (1.0f + erff(v * 0.70710678118654752f));
          if (rowg < M && colg < N)
            Cv[(size_t)z * (size_t)sC + (size_t)rowg * ldc + colg] = f2bf(v);
        }
      }
    }
  }
}

// ---------------------------------------------------------------------------
// Flash attention (non-causal), QBLK=128 (4 waves x 32 q-rows), KVBLK=64.
// Q-RoPE fused at fragment load; K arrives pre-roped. Exact per-tile rescale
// (R8-proven); row-sum via MFMA against all-ones B fragment.
// ---------------------------------------------------------------------------
__global__ __launch_bounds__(256) void attn_kernel(const u16* __restrict__ Q,
                                                   const u16* __restrict__ Km,
                                                   const u16* __restrict__ Vmt,
                                                   u16* __restrict__ Y,
                                                   const float* __restrict__ ct,
                                                   const float* __restrict__ st) {
  __shared__ alignas(16) u16 Ks[64][136];
  __shared__ alignas(16) u16 Vts[128][72];
  __shared__ alignas(16) u16 Ps[4][32][72];
  const int qt = blockIdx.x;
  const int bh = blockIdx.y;
  const int b = bh >> 3, h = bh & 7;
  const int tid = threadIdx.x;
  const int w = tid >> 6, lane = tid & 63;
  const int l15 = lane & 15, l4 = lane >> 4;
  const size_t qbase = (size_t)b * 1000 * 1024 + h * HS_;
  const size_t kbase = (size_t)b * 1024000 + h * HS_;
  const size_t vbase = (size_t)b * 1048576 + (size_t)(h * HS_) * 1024;
  const int q0 = qt * 128 + w * 32;
  s16x8 aq[2][4];
#pragma unroll
  for (int qf = 0; qf < 2; ++qf) {
    const int qrow = q0 + qf * 16 + l15;
#pragma unroll
    for (int c = 0; c < 4; ++c) {
      s16x8 v = {};
      if (qrow < T_) {
        v = *(const s16x8*)(Q + qbase + (size_t)qrow * 1024 + c * 32 + l4 * 8);
        rope8(v, ct, st, qrow, c * 16 + l4 * 4);
      }
      aq[qf][c] = v;
    }
  }
  s16x8 ones;
#pragma unroll
  for (int j = 0; j < 8; ++j) ones[j] = (short)0x3F80;   // bf16 1.0
  f32x4 acc[2][8] = {};
  f32x4 lsum[2] = {};
  float m_run[2][4];
#pragma unroll
  for (int qf = 0; qf < 2; ++qf)
#pragma unroll
    for (int r = 0; r < 4; ++r) m_run[qf][r] = -1e30f;
  const float SCALE = 0.08838834764831845f;
  for (int kt = 0; kt < 16; ++kt) {
    {
      const int r = tid >> 2, c0 = (tid & 3) << 5;
      const int kk = kt * 64 + r;
#pragma unroll
      for (int v = 0; v < 4; ++v) {
        s16x8 val = {};
        if (kk < T_) val = *(const s16x8*)(Km + kbase + (size_t)kk * 1024 + c0 + v * 8);
        *(s16x8*)&Ks[r][c0 + v * 8] = val;
      }
      const int r2 = tid >> 1, c2s = (tid & 1) << 5;
#pragma unroll
      for (int v = 0; v < 4; ++v) {
        const s16x8 val = *(const s16x8*)(Vmt + vbase + (size_t)r2 * 1024 + kt * 64 + c2s + v * 8);
        *(s16x8*)&Vts[r2][c2s + v * 8] = val;
      }
    }
    __syncthreads();
    f32x4 sacc[2][4] = {};
#pragma unroll
    for (int c = 0; c < 4; ++c) {
      s16x8 bk[4];
#pragma unroll
      for (int f = 0; f < 4; ++f) bk[f] = *(const s16x8*)&Ks[f * 16 + l15][c * 32 + l4 * 8];
#pragma unroll
      for (int qf = 0; qf < 2; ++qf)
#pragma unroll
        for (int f = 0; f < 4; ++f) MFMA(sacc[qf][f], aq[qf][c], bk[f]);
    }
    asm volatile("s_nop 7\n\ts_nop 7"
                 : "+v"(sacc[0][0]), "+v"(sacc[0][1]), "+v"(sacc[0][2]), "+v"(sacc[0][3]),
                   "+v"(sacc[1][0]), "+v"(sacc[1][1]), "+v"(sacc[1][2]), "+v"(sacc[1][3]));
#pragma unroll
    for (int qf = 0; qf < 2; ++qf) {
      float sv[4][4];
#pragma unroll
      for (int f = 0; f < 4; ++f) {
        const int key = kt * 64 + f * 16 + l15;
#pragma unroll
        for (int r = 0; r < 4; ++r) sv[f][r] = (key < T_) ? sacc[qf][f][r] * SCALE : -1e30f;
      }
#pragma unroll
      for (int r = 0; r < 4; ++r) {
        float mx = fmaxf(fmaxf(sv[0][r], sv[1][r]), fmaxf(sv[2][r], sv[3][r]));
#pragma unroll
        for (int off = 8; off >= 1; off >>= 1) mx = fmaxf(mx, __shfl_xor(mx, off));
        const float mn = fmaxf(m_run[qf][r], mx);
        const float corr = __expf(m_run[qf][r] - mn);
        m_run[qf][r] = mn;
#pragma unroll
        for (int f = 0; f < 4; ++f)
          Ps[w][qf * 16 + l4 * 4 + r][f * 16 + l15] = f2bf(__expf(sv[f][r] - mn));
        lsum[qf][r] *= corr;
#pragma unroll
        for (int n = 0; n < 8; ++n) acc[qf][n][r] *= corr;
      }
    }
    asm volatile("s_waitcnt lgkmcnt(0)" ::: "memory");   // own-wave Ps visible
    // O += P V ; lsum += P * ones (row-sum via MFMA)
#pragma unroll
    for (int c2 = 0; c2 < 2; ++c2) {
      s16x8 pa[2];
#pragma unroll
      for (int qf = 0; qf < 2; ++qf)
        pa[qf] = *(const s16x8*)&Ps[w][qf * 16 + l15][c2 * 32 + l4 * 8];
      MFMA(lsum[0], pa[0], ones);
      MFMA(lsum[1], pa[1], ones);
#pragma unroll
      for (int n = 0; n < 8; ++n) {
        const s16x8 vb = *(const s16x8*)&Vts[n * 16 + l15][c2 * 32 + l4 * 8];
#pragma unroll
        for (int qf = 0; qf < 2; ++qf) MFMA(acc[qf][n], pa[qf], vb);
      }
    }
    __syncthreads();
  }
  asm volatile("s_nop 7\n\ts_nop 7"
               : "+v"(acc[0][6]), "+v"(acc[0][7]), "+v"(acc[1][6]), "+v"(acc[1][7]),
                 "+v"(lsum[0]), "+v"(lsum[1]));
#pragma unroll
  for (int qf = 0; qf < 2; ++qf)
#pragma unroll
    for (int n = 0; n < 8; ++n)
#pragma unroll
      for (int r = 0; r < 4; ++r) {
        const int q = q0 + qf * 16 + l4 * 4 + r;
        if (q < T_)
          Y[(size_t)(b * 1000 + q) * 1024 + h * HS_ + n * 16 + l15] =
              f2bf(acc[qf][n][r] / lsum[qf][r]);
      }
}

// ---------------------------------------------------------------------------
// src = LN(src + bf16 add) * g + b  (fp32 master) + bf16 mirror. Vectorized.
// ---------------------------------------------------------------------------
__global__ __launch_bounds__(256) void addln_kernel(float* __restrict__ src,
                                                    const u16* __restrict__ add,
                                                    const float* __restrict__ g,
                                                    const float* __restrict__ bb,
                                                    u16* __restrict__ outb) {
  const int row = blockIdx.x;
  const int tid = threadIdx.x;
  const int d = tid * 4;
  float* s = src + (size_t)row * D_;
  const u16* a = add + (size_t)row * D_;
  f32x4 sv = *(const f32x4*)(s + d);
  const u16x4 av = *(const u16x4*)(a + d);
  float x[4];
  float sum = 0.f, sq = 0.f;
#pragma unroll
  for (int i = 0; i < 4; ++i) {
    const float v = sv[i] + bf2f(av[i]);
    x[i] = v; sum += v; sq += v * v;
  }
#pragma unroll
  for (int off = 32; off >= 1; off >>= 1) { sum += __shfl_xor(sum, off); sq += __shfl_xor(sq, off); }
  __shared__ float red[8];
  const int wid = tid >> 6;
  if ((tid & 63) == 0) { red[wid] = sum; red[4 + wid] = sq; }
  __syncthreads();
  sum = red[0] + red[1] + red[2] + red[3];
  sq = red[4] + red[5] + red[6] + red[7];
  const float mean = sum * (1.f / 1024.f);
  const float var = sq * (1.f / 1024.f) - mean * mean;
  const float rstd = rsqrtf(var + 1e-5f);
  const f32x4 gv = *(const f32x4*)(g + d);
  const f32x4 bv = *(const f32x4*)(bb + d);
  f32x4 yv;
  u16x4 ob;
#pragma unroll
  for (int i = 0; i < 4; ++i) {
    const float y = (x[i] - mean) * rstd * gv[i] + bv[i];
    yv[i] = y;
    ob[i] = f2bf(y);
  }
  *(f32x4*)(s + d) = yv;
  *(u16x4*)(outb + (size_t)row * D_ + d) = ob;
}

// ---------------------------------------------------------------------------
// Host orchestration
// ---------------------------------------------------------------------------
static inline int cdiv(int a, int b) { return (a + b - 1) / b; }

extern "C" void kernel_launch(void* const* d_in, const int* in_sizes, int n_in,
                              void* d_out, int out_size, void* d_ws, size_t ws_size,
                              hipStream_t stream) {
  const float* x    = (const float*)d_in[0];
  const float* Wq   = (const float*)d_in[1];
  const float* Wk   = (const float*)d_in[2];
  const float* Wv   = (const float*)d_in[3];
  const float* Wpk  = (const float*)d_in[4];
  const float* bpk  = (const float*)d_in[5];
  const float* Wpv  = (const float*)d_in[6];
  const float* bpv  = (const float*)d_in[7];
  const float* g1   = (const float*)d_in[8];
  const float* b1ln = (const float*)d_in[9];
  const float* W1   = (const float*)d_in[10];
  const float* b1   = (const float*)d_in[11];
  const float* W2   = (const float*)d_in[12];
  const float* b2   = (const float*)d_in[13];
  const float* g2   = (const float*)d_in[14];
  const float* b2ln = (const float*)d_in[15];

  char* wsb = (char*)d_ws;
  float* cosT = (float*)(wsb + 0);                //   256 KB
  float* sinT = (float*)(wsb + 262144);           //   256 KB
  float* srcf = (float*)(wsb + 524288);           // 32.77 MB fp32 residual
  u16* srcb   = (u16*)(wsb + 33292288);           // 16.38 MB bf16 mirror
  u16* Qb     = (u16*)(wsb + 49676288);           // 16.38 MB [8000][1024]
  u16* KTg    = (u16*)(wsb + 66060288);           // 16.78 MB [8][1024 d][1024 t]
  u16* VTg    = (u16*)(wsb + 82837504);           // 16.78 MB [8][1024 d][1024 t]
  u16* Km     = (u16*)(wsb + 99614720);           // 16.38 MB [8][1000][1024]
  u16* Vmt    = (u16*)(wsb + 115998720);          // 16.78 MB [8][1024 d][1024 u]
  u16* yB     = (u16*)(wsb + 132775936);          // 16.38 MB [8000][1024] bf16 y
  u16* wbuf   = (u16*)(wsb + 149159936);          // 27.07 MB layer weights
  u16* hB     = Qb;  // [8000][4096] overlaps Qb+KTg+VTg+Km (all dead at FFN time)

  u16* wqB  = wbuf + 0;          // [3072][1024] fused q,k,v
  u16* wpkB = wbuf + 3145728;    // [1000][1000]
  u16* wpvB = wbuf + 4145728;
  u16* w1B  = wbuf + 5145728;    // [4096][1024]
  u16* w2B  = wbuf + 9340032;    // [1024][4096]

  tab_kernel<<<250, 256, 0, stream>>>(cosT, sinT);
  zerotail_kernel<<<2304, 256, 0, stream>>>(KTg, VTg, Vmt);
  hipMemcpyAsync(srcf, x, (size_t)BT_ * D_ * sizeof(float), hipMemcpyDeviceToDevice, stream);
  convert_kernel<<<cdiv(BT_ * D_, 1024), 256, 0, stream>>>(x, srcb, BT_ * D_);

  for (int l = 0; l < 4; ++l) {
    convertL_kernel<<<13218, 256, 0, stream>>>(
        Wq + (size_t)l * 1048576, Wk + (size_t)l * 1048576, Wv + (size_t)l * 1048576,
        Wpk + (size_t)l * 1000000, Wpv + (size_t)l * 1000000,
        W1 + (size_t)l * 4194304, W2 + (size_t)l * 4194304,
        wqB, wpkB, wpvB, w1B, w2B);

    // Fused QKV (split epilogue): Q -> Qb, K^T -> KTg, V^T -> VTg
    gemm2p<0, false, false, true><<<dim3(24, 63, 1), 256, 0, stream>>>(
        srcb, wqB, Qb, nullptr, nullptr, nullptr, KTg, VTg,
        BT_, 3072, 1024, 1024, 1024, 1024, 0, 0, 0);

    // K position-mix + fused K-RoPE
    gemm2p<1, false, true, false><<<dim3(8, 8, 8), 256, 0, stream>>>(
        wpkB, KTg, Km, bpk + (size_t)l * 1000, cosT, sinT, nullptr, nullptr,
        1000, 1024, 1024, 1000, 1024, 1024, 0L, 1048576L, 1024000L);

    // V position-mix (transposed out)
    gemm2p<2, false, false, false><<<dim3(8, 8, 8), 256, 0, stream>>>(
        VTg, wpvB, Vmt, bpv + (size_t)l * 1000, nullptr, nullptr, nullptr, nullptr,
        1024, 1000, 1024, 1024, 1000, 1024, 1048576L, 0L, 1048576L);

    // Attention (Q-rope fused; K pre-roped), bf16 out
    attn_kernel<<<dim3(8, 64), 256, 0, stream>>>(Qb, Km, Vmt, yB, cosT, sinT);

    addln_kernel<<<BT_, 256, 0, stream>>>(srcf, yB, g1 + (size_t)l * 1024,
                                          b1ln + (size_t)l * 1024, srcb);

    // FFN1 (+bias+gelu) -> bf16 h
    gemm2p<2, true, false, false><<<dim3(32, 63, 1), 256, 0, stream>>>(
        srcb, w1B, hB, b1 + (size_t)l * 4096, nullptr, nullptr, nullptr, nullptr,
        BT_, 4096, 1024, 1024, 1024, 4096, 0, 0, 0);
    // FFN2 (+bias) -> bf16 yB
    gemm2p<2, false, false, false><<<dim3(8, 63, 1), 256, 0, stream>>>(
        hB, w2B, yB, b2 + (size_t)l * 1024, nullptr, nullptr, nullptr, nullptr,
        BT_, 1024, 4096, 4096, 4096, 1024, 0, 0, 0);

    addln_kernel<<<BT_, 256, 0, stream>>>(srcf, yB, g2 + (size_t)l * 1024,
                                          b2ln + (size_t)l * 1024, srcb);
  }

  hipMemcpyAsync(d_out, srcf, (size_t)BT_ * D_ * sizeof(float), hipMemcpyDeviceToDevice, stream);
}

// Round 11
// 2028.659 us; speedup vs baseline: 1.2871x; 1.0406x over previous
//
#include <hip/hip_runtime.h>
#include <cstdint>
#include <cstddef>

// ---------------------------------------------------------------------------
// SelfAttentionTransformer on MI355X (gfx950).
// L=4, D=1024, H=8, HS=128, T=1000, DFF=4096, B=8.
// R11: R10 + bf16-only residual master (srcf dropped, both memcpys dropped,
//      addln reads/writes bf16; final addln writes fp32 d_out directly).
// ---------------------------------------------------------------------------

typedef unsigned short u16;
typedef unsigned int u32;
typedef __attribute__((ext_vector_type(8))) short s16x8;   // 8 bf16 raw bits
typedef __attribute__((ext_vector_type(4))) float f32x4;
typedef __attribute__((ext_vector_type(4))) unsigned short u16x4;

#define DEV static __device__ __forceinline__

DEV float bf2f(u16 u) { union { u32 u; float f; } v; v.u = ((u32)u) << 16; return v.f; }
DEV u16 f2bf(float f) {
  union { float f; u32 u; } v; v.f = f;
  return (u16)((v.u + 0x7fffu + ((v.u >> 16) & 1u)) >> 16);   // RNE
}

#define MFMA(acc_, a_, b_) \
  asm volatile("v_mfma_f32_16x16x32_bf16 %0, %1, %2, %0" : "+v"(acc_) : "v"(a_), "v"(b_))

#define GLD16(g_, l_) \
  __builtin_amdgcn_global_load_lds((const __attribute__((address_space(1))) void*)(g_), \
                                   (__attribute__((address_space(3))) void*)(l_), 16, 0, 0)

static constexpr int T_ = 1000, D_ = 1024, H_ = 8, HS_ = 128, B_ = 8;
static constexpr int BT_ = B_ * T_;   // 8000

// rope on 8 packed bf16 (4 pairs), table base i0 (pair index of element 0).
DEV void rope8(s16x8& v, const float* __restrict__ ct, const float* __restrict__ st,
               int t, int i0) {
  const f32x4 c4 = *(const f32x4*)(ct + t * 64 + i0);
  const f32x4 s4 = *(const f32x4*)(st + t * 64 + i0);
#pragma unroll
  for (int p = 0; p < 4; ++p) {
    const float xr = bf2f((u16)v[2 * p]), xi = bf2f((u16)v[2 * p + 1]);
    v[2 * p]     = (short)f2bf(xr * c4[p] - xi * s4[p]);
    v[2 * p + 1] = (short)f2bf(xr * s4[p] + xi * c4[p]);
  }
}

// ---------------------------------------------------------------------------
__global__ void tab_kernel(float* __restrict__ ct, float* __restrict__ st) {
  const int id = blockIdx.x * 256 + threadIdx.x;   // 64000
  const int i = id & 63, t = id >> 6;
  const float theta = powf(10000.f, -(float)i * (1.f / 64.f));
  const float ang = (float)t * theta;
  ct[id] = cosf(ang);
  st[id] = sinf(ang);
}

__global__ void convert_kernel(const float* __restrict__ in, u16* __restrict__ out, int n) {
  const int i = (blockIdx.x * 256 + threadIdx.x) * 4;
  if (i < n) {
    const float4 v = *(const float4*)(in + i);
    uint2 pk;
    pk.x = (u32)f2bf(v.x) | ((u32)f2bf(v.y) << 16);
    pk.y = (u32)f2bf(v.z) | ((u32)f2bf(v.w) << 16);
    *(uint2*)(out + i) = pk;
  }
}

// All 7 per-layer weight converts fused (float4 quads, segmented).
__global__ __launch_bounds__(256) void convertL_kernel(
    const float* __restrict__ Wq, const float* __restrict__ Wk, const float* __restrict__ Wv,
    const float* __restrict__ Wpk, const float* __restrict__ Wpv,
    const float* __restrict__ W1, const float* __restrict__ W2,
    u16* __restrict__ wq, u16* __restrict__ wpk, u16* __restrict__ wpv,
    u16* __restrict__ w1, u16* __restrict__ w2) {
  const int i = blockIdx.x * 256 + threadIdx.x;
  const float* src; u16* dst; int j;
  if      (i <  262144) { src = Wq;  dst = wq;            j = i; }
  else if (i <  524288) { src = Wk;  dst = wq + 1048576;  j = i -  262144; }
  else if (i <  786432) { src = Wv;  dst = wq + 2097152;  j = i -  524288; }
  else if (i < 1036432) { src = Wpk; dst = wpk;           j = i -  786432; }
  else if (i < 1286432) { src = Wpv; dst = wpv;           j = i - 1036432; }
  else if (i < 2335008) { src = W1;  dst = w1;            j = i - 1286432; }
  else if (i < 3383584) { src = W2;  dst = w2;            j = i - 2335008; }
  else return;
  const float4 v = ((const float4*)src)[j];
  uint2 pk;
  pk.x = (u32)f2bf(v.x) | ((u32)f2bf(v.y) << 16);
  pk.y = (u32)f2bf(v.z) | ((u32)f2bf(v.w) << 16);
  ((uint2*)dst)[j] = pk;
}

// Zero the t/u in [1000,1024) tails of KTg, VTg, Vmt ([8][1024][1024] each).
__global__ void zerotail_kernel(u16* __restrict__ KTg, u16* __restrict__ VTg,
                                u16* __restrict__ Vmt) {
  const int id = blockIdx.x * 256 + threadIdx.x;   // 3 * 8192 * 24 = 589824
  if (id >= 3 * 8192 * 24) return;
  const int which = id / 196608, rem = id % 196608;
  const int bd = rem / 24, t = 1000 + rem % 24;
  u16* p = (which == 0) ? KTg : (which == 1) ? VTg : Vmt;
  p[(size_t)bd * 1024 + t] = 0;
}

// ---------------------------------------------------------------------------
// gemm2p: proven 128x128 / BK=32 / 256-thread / double-buffered NT GEMM.
// RK: fuse K-RoPE into epilogue (t = row u, pairs along d via shfl_xor).
// SPLIT: QKV mode — cols<1024 -> Cv(Q); [1024,2048) -> KT^T; [2048,3072) -> VT^T.
// Output bf16. Requires K%32==0. M/N tails via clamp + store guard.
// ---------------------------------------------------------------------------
template <int BIAS, bool ACT, bool RK, bool SPLIT>   // BIAS: 0 none, 1 row, 2 col
__global__ __launch_bounds__(256) void gemm2p(
    const u16* __restrict__ A, const u16* __restrict__ B, u16* __restrict__ Cv,
    const float* __restrict__ bias, const float* __restrict__ ct,
    const float* __restrict__ st, u16* __restrict__ KT, u16* __restrict__ VT,
    int M, int N, int K, int lda, int ldb, int ldc, long sA, long sB, long sC) {
  __shared__ alignas(16) u16 As[2][4096];
  __shared__ alignas(16) u16 Bs[2][4096];
  const int z = blockIdx.z;
  A += (size_t)z * (size_t)sA;
  B += (size_t)z * (size_t)sB;
  const int m0 = blockIdx.y * 128, n0 = blockIdx.x * 128;
  const int tid = threadIdx.x;
  const int wid = tid >> 6, lane = tid & 63;
  const int wr = wid >> 1, wc = wid & 1;
  const int l15 = lane & 15, l4 = lane >> 4;
  const int srow = tid >> 2;
  const int sg = ((tid & 3) ^ ((tid >> 3) & 3)) << 3;
  const u16* gA0 = A + (size_t)min(m0 + srow, M - 1) * lda + sg;
  const u16* gA1 = A + (size_t)min(m0 + 64 + srow, M - 1) * lda + sg;
  const u16* gB0 = B + (size_t)min(n0 + srow, N - 1) * ldb + sg;
  const u16* gB1 = B + (size_t)min(n0 + 64 + srow, N - 1) * ldb + sg;
  const int gg = (l4 ^ ((l15 >> 1) & 3)) << 3;
  const int aBase = (wr * 64 + l15) * 32 + gg;
  const int bBase = (wc * 64 + l15) * 32 + gg;

  f32x4 acc[4][4] = {};
  const int KTn = K >> 5;
  GLD16(gA0, &As[0][tid * 8]);
  GLD16(gA1, &As[0][(256 + tid) * 8]);
  GLD16(gB0, &Bs[0][tid * 8]);
  GLD16(gB1, &Bs[0][(256 + tid) * 8]);
  __syncthreads();
  int cur = 0;
#pragma unroll 1
  for (int kt = 0; kt < KTn; ++kt) {
    if (kt + 1 < KTn) {
      const int kb = (kt + 1) << 5;
      GLD16(gA0 + kb, &As[cur ^ 1][tid * 8]);
      GLD16(gA1 + kb, &As[cur ^ 1][(256 + tid) * 8]);
      GLD16(gB0 + kb, &Bs[cur ^ 1][tid * 8]);
      GLD16(gB1 + kb, &Bs[cur ^ 1][(256 + tid) * 8]);
    }
    s16x8 af[4], bfr[4];
#pragma unroll
    for (int i = 0; i < 4; ++i) af[i] = *(const s16x8*)&As[cur][aBase + i * 512];
#pragma unroll
    for (int i = 0; i < 4; ++i) bfr[i] = *(const s16x8*)&Bs[cur][bBase + i * 512];
    __builtin_amdgcn_s_setprio(1);
#pragma unroll
    for (int mi = 0; mi < 4; ++mi)
#pragma unroll
      for (int ni = 0; ni < 4; ++ni) MFMA(acc[mi][ni], af[mi], bfr[ni]);
    __builtin_amdgcn_s_setprio(0);
    __syncthreads();
    cur ^= 1;
  }
  asm volatile("s_nop 7\n\ts_nop 7"
               : "+v"(acc[3][0]), "+v"(acc[3][1]), "+v"(acc[3][2]), "+v"(acc[3][3]));
  if constexpr (SPLIT) {
#pragma unroll
    for (int mi = 0; mi < 4; ++mi) {
      const int rb = m0 + wr * 64 + mi * 16 + l4 * 4;   // multiple of 4
      if (rb < M) {
#pragma unroll
        for (int ni = 0; ni < 4; ++ni) {
          const int colg = n0 + wc * 64 + ni * 16 + l15;
          if (colg < 1024) {
#pragma unroll
            for (int r = 0; r < 4; ++r)
              Cv[(size_t)(rb + r) * 1024 + colg] = f2bf(acc[mi][ni][r]);
          } else {
            u16* dst = (colg < 2048) ? KT : VT;
            const int dcol = colg & 1023;
            const int bq = rb / 1000;
            const int tq = rb - bq * 1000;   // mult of 4, <=996: no straddle
            u16x4 pk;
#pragma unroll
            for (int r = 0; r < 4; ++r) pk[r] = f2bf(acc[mi][ni][r]);
            *(u16x4*)(dst + (size_t)bq * 1048576 + (size_t)dcol * 1024 + tq) = pk;
          }
        }
      }
    }
  } else {
#pragma unroll
    for (int mi = 0; mi < 4; ++mi) {
#pragma unroll
      for (int ni = 0; ni < 4; ++ni) {
        const int colg = n0 + wc * 64 + ni * 16 + l15;
#pragma unroll
        for (int r = 0; r < 4; ++r) {
          const int rowg = m0 + wr * 64 + mi * 16 + l4 * 4 + r;
          float v = acc[mi][ni][r];
          if (BIAS == 1) v += bias[min(rowg, M - 1)];
          if (BIAS == 2) v += bias[min(colg, N - 1)];
          if constexpr (RK) {
            // K rope: t = rowg (position u), pair along d: partner lane l15^1.
            const int tt = min(rowg, T_ - 1);
            const int ii = (colg & 127) >> 1;
            const float c = ct[tt * 64 + ii], s = st[tt * 64 + ii];
            const float partner = __shfl_xor(v, 1);
            v = (colg & 1) ? (partner * s + v * c) : (v * c - partner * s);
          }
          if (ACT) v = 0.5f * v * (1.0f + erff(v * 0.70710678118654752f));
          if (rowg < M && colg < N)
            Cv[(size_t)z * (size_t)sC + (size_t)rowg * ldc + colg] = f2bf(v);
        }
      }
    }
  }
}

// ---------------------------------------------------------------------------
// Flash attention (non-causal), QBLK=128 (4 waves x 32 q-rows), KVBLK=64.
// Q-RoPE fused at fragment load; K arrives pre-roped. Exact per-tile rescale;
// row-sum via MFMA against all-ones B fragment.
// ---------------------------------------------------------------------------
__global__ __launch_bounds__(256) void attn_kernel(const u16* __restrict__ Q,
                                                   const u16* __restrict__ Km,
                                                   const u16* __restrict__ Vmt,
                                                   u16* __restrict__ Y,
                                                   const float* __restrict__ ct,
                                                   const float* __restrict__ st) {
  __shared__ alignas(16) u16 Ks[64][136];
  __shared__ alignas(16) u16 Vts[128][72];
  __shared__ alignas(16) u16 Ps[4][32][72];
  const int qt = blockIdx.x;
  const int bh = blockIdx.y;
  const int b = bh >> 3, h = bh & 7;
  const int tid = threadIdx.x;
  const int w = tid >> 6, lane = tid & 63;
  const int l15 = lane & 15, l4 = lane >> 4;
  const size_t qbase = (size_t)b * 1000 * 1024 + h * HS_;
  const size_t kbase = (size_t)b * 1024000 + h * HS_;
  const size_t vbase = (size_t)b * 1048576 + (size_t)(h * HS_) * 1024;
  const int q0 = qt * 128 + w * 32;
  s16x8 aq[2][4];
#pragma unroll
  for (int qf = 0; qf < 2; ++qf) {
    const int qrow = q0 + qf * 16 + l15;
#pragma unroll
    for (int c = 0; c < 4; ++c) {
      s16x8 v = {};
      if (qrow < T_) {
        v = *(const s16x8*)(Q + qbase + (size_t)qrow * 1024 + c * 32 + l4 * 8);
        rope8(v, ct, st, qrow, c * 16 + l4 * 4);
      }
      aq[qf][c] = v;
    }
  }
  s16x8 ones;
#pragma unroll
  for (int j = 0; j < 8; ++j) ones[j] = (short)0x3F80;   // bf16 1.0
  f32x4 acc[2][8] = {};
  f32x4 lsum[2] = {};
  float m_run[2][4];
#pragma unroll
  for (int qf = 0; qf < 2; ++qf)
#pragma unroll
    for (int r = 0; r < 4; ++r) m_run[qf][r] = -1e30f;
  const float SCALE = 0.08838834764831845f;
  for (int kt = 0; kt < 16; ++kt) {
    {
      const int r = tid >> 2, c0 = (tid & 3) << 5;
      const int kk = kt * 64 + r;
#pragma unroll
      for (int v = 0; v < 4; ++v) {
        s16x8 val = {};
        if (kk < T_) val = *(const s16x8*)(Km + kbase + (size_t)kk * 1024 + c0 + v * 8);
        *(s16x8*)&Ks[r][c0 + v * 8] = val;
      }
      const int r2 = tid >> 1, c2s = (tid & 1) << 5;
#pragma unroll
      for (int v = 0; v < 4; ++v) {
        const s16x8 val = *(const s16x8*)(Vmt + vbase + (size_t)r2 * 1024 + kt * 64 + c2s + v * 8);
        *(s16x8*)&Vts[r2][c2s + v * 8] = val;
      }
    }
    __syncthreads();
    f32x4 sacc[2][4] = {};
#pragma unroll
    for (int c = 0; c < 4; ++c) {
      s16x8 bk[4];
#pragma unroll
      for (int f = 0; f < 4; ++f) bk[f] = *(const s16x8*)&Ks[f * 16 + l15][c * 32 + l4 * 8];
#pragma unroll
      for (int qf = 0; qf < 2; ++qf)
#pragma unroll
        for (int f = 0; f < 4; ++f) MFMA(sacc[qf][f], aq[qf][c], bk[f]);
    }
    asm volatile("s_nop 7\n\ts_nop 7"
                 : "+v"(sacc[0][0]), "+v"(sacc[0][1]), "+v"(sacc[0][2]), "+v"(sacc[0][3]),
                   "+v"(sacc[1][0]), "+v"(sacc[1][1]), "+v"(sacc[1][2]), "+v"(sacc[1][3]));
#pragma unroll
    for (int qf = 0; qf < 2; ++qf) {
      float sv[4][4];
#pragma unroll
      for (int f = 0; f < 4; ++f) {
        const int key = kt * 64 + f * 16 + l15;
#pragma unroll
        for (int r = 0; r < 4; ++r) sv[f][r] = (key < T_) ? sacc[qf][f][r] * SCALE : -1e30f;
      }
#pragma unroll
      for (int r = 0; r < 4; ++r) {
        float mx = fmaxf(fmaxf(sv[0][r], sv[1][r]), fmaxf(sv[2][r], sv[3][r]));
#pragma unroll
        for (int off = 8; off >= 1; off >>= 1) mx = fmaxf(mx, __shfl_xor(mx, off));
        const float mn = fmaxf(m_run[qf][r], mx);
        const float corr = __expf(m_run[qf][r] - mn);
        m_run[qf][r] = mn;
#pragma unroll
        for (int f = 0; f < 4; ++f)
          Ps[w][qf * 16 + l4 * 4 + r][f * 16 + l15] = f2bf(__expf(sv[f][r] - mn));
        lsum[qf][r] *= corr;
#pragma unroll
        for (int n = 0; n < 8; ++n) acc[qf][n][r] *= corr;
      }
    }
    asm volatile("s_waitcnt lgkmcnt(0)" ::: "memory");   // own-wave Ps visible
    // O += P V ; lsum += P * ones (row-sum via MFMA)
#pragma unroll
    for (int c2 = 0; c2 < 2; ++c2) {
      s16x8 pa[2];
#pragma unroll
      for (int qf = 0; qf < 2; ++qf)
        pa[qf] = *(const s16x8*)&Ps[w][qf * 16 + l15][c2 * 32 + l4 * 8];
      MFMA(lsum[0], pa[0], ones);
      MFMA(lsum[1], pa[1], ones);
#pragma unroll
      for (int n = 0; n < 8; ++n) {
        const s16x8 vb = *(const s16x8*)&Vts[n * 16 + l15][c2 * 32 + l4 * 8];
#pragma unroll
        for (int qf = 0; qf < 2; ++qf) MFMA(acc[qf][n], pa[qf], vb);
      }
    }
    __syncthreads();
  }
  asm volatile("s_nop 7\n\ts_nop 7"
               : "+v"(acc[0][6]), "+v"(acc[0][7]), "+v"(acc[1][6]), "+v"(acc[1][7]),
                 "+v"(lsum[0]), "+v"(lsum[1]));
#pragma unroll
  for (int qf = 0; qf < 2; ++qf)
#pragma unroll
    for (int n = 0; n < 8; ++n)
#pragma unroll
      for (int r = 0; r < 4; ++r) {
        const int q = q0 + qf * 16 + l4 * 4 + r;
        if (q < T_)
          Y[(size_t)(b * 1000 + q) * 1024 + h * HS_ + n * 16 + l15] =
              f2bf(acc[qf][n][r] / lsum[qf][r]);
      }
}

// ---------------------------------------------------------------------------
// srcb = LN(srcb + add) * g + b   — bf16 residual master, fp32 math inside.
// FINAL: also write the fp32 result to outf (the harness output).
// ---------------------------------------------------------------------------
template <bool FINAL>
__global__ __launch_bounds__(256) void addln_kernel(u16* __restrict__ srcb,
                                                    const u16* __restrict__ add,
                                                    const float* __restrict__ g,
                                                    const float* __restrict__ bb,
                                                    float* __restrict__ outf) {
  const int row = blockIdx.x;
  const int tid = threadIdx.x;
  const int d = tid * 4;
  u16* s = srcb + (size_t)row * D_;
  const u16* a = add + (size_t)row * D_;
  const u16x4 sv = *(const u16x4*)(s + d);
  const u16x4 av = *(const u16x4*)(a + d);
  float x[4];
  float sum = 0.f, sq = 0.f;
#pragma unroll
  for (int i = 0; i < 4; ++i) {
    const float v = bf2f(sv[i]) + bf2f(av[i]);
    x[i] = v; sum += v; sq += v * v;
  }
#pragma unroll
  for (int off = 32; off >= 1; off >>= 1) { sum += __shfl_xor(sum, off); sq += __shfl_xor(sq, off); }
  __shared__ float red[8];
  const int wid = tid >> 6;
  if ((tid & 63) == 0) { red[wid] = sum; red[4 + wid] = sq; }
  __syncthreads();
  sum = red[0] + red[1] + red[2] + red[3];
  sq = red[4] + red[5] + red[6] + red[7];
  const float mean = sum * (1.f / 1024.f);
  const float var = sq * (1.f / 1024.f) - mean * mean;
  const float rstd = rsqrtf(var + 1e-5f);
  const f32x4 gv = *(const f32x4*)(g + d);
  const f32x4 bv = *(const f32x4*)(bb + d);
  f32x4 yv;
  u16x4 ob;
#pragma unroll
  for (int i = 0; i < 4; ++i) {
    const float y = (x[i] - mean) * rstd * gv[i] + bv[i];
    yv[i] = y;
    ob[i] = f2bf(y);
  }
  *(u16x4*)(s + d) = ob;
  if (FINAL) *(f32x4*)(outf + (size_t)row * D_ + d) = yv;
}

// ---------------------------------------------------------------------------
// Host orchestration
// ---------------------------------------------------------------------------
static inline int cdiv(int a, int b) { return (a + b - 1) / b; }

extern "C" void kernel_launch(void* const* d_in, const int* in_sizes, int n_in,
                              void* d_out, int out_size, void* d_ws, size_t ws_size,
                              hipStream_t stream) {
  const float* x    = (const float*)d_in[0];
  const float* Wq   = (const float*)d_in[1];
  const float* Wk   = (const float*)d_in[2];
  const float* Wv   = (const float*)d_in[3];
  const float* Wpk  = (const float*)d_in[4];
  const float* bpk  = (const float*)d_in[5];
  const float* Wpv  = (const float*)d_in[6];
  const float* bpv  = (const float*)d_in[7];
  const float* g1   = (const float*)d_in[8];
  const float* b1ln = (const float*)d_in[9];
  const float* W1   = (const float*)d_in[10];
  const float* b1   = (const float*)d_in[11];
  const float* W2   = (const float*)d_in[12];
  const float* b2   = (const float*)d_in[13];
  const float* g2   = (const float*)d_in[14];
  const float* b2ln = (const float*)d_in[15];

  char* wsb = (char*)d_ws;
  float* cosT = (float*)(wsb + 0);                //   256 KB
  float* sinT = (float*)(wsb + 262144);           //   256 KB
  u16* srcb   = (u16*)(wsb + 33292288);           // 16.38 MB bf16 residual master
  u16* Qb     = (u16*)(wsb + 49676288);           // 16.38 MB [8000][1024]
  u16* KTg    = (u16*)(wsb + 66060288);           // 16.78 MB [8][1024 d][1024 t]
  u16* VTg    = (u16*)(wsb + 82837504);           // 16.78 MB [8][1024 d][1024 t]
  u16* Km     = (u16*)(wsb + 99614720);           // 16.38 MB [8][1000][1024]
  u16* Vmt    = (u16*)(wsb + 115998720);          // 16.78 MB [8][1024 d][1024 u]
  u16* yB     = (u16*)(wsb + 132775936);          // 16.38 MB [8000][1024] bf16 y
  u16* wbuf   = (u16*)(wsb + 149159936);          // 27.07 MB layer weights
  u16* hB     = Qb;  // [8000][4096] overlaps Qb+KTg+VTg+Km (all dead at FFN time)

  u16* wqB  = wbuf + 0;          // [3072][1024] fused q,k,v
  u16* wpkB = wbuf + 3145728;    // [1000][1000]
  u16* wpvB = wbuf + 4145728;
  u16* w1B  = wbuf + 5145728;    // [4096][1024]
  u16* w2B  = wbuf + 9340032;    // [1024][4096]

  tab_kernel<<<250, 256, 0, stream>>>(cosT, sinT);
  zerotail_kernel<<<2304, 256, 0, stream>>>(KTg, VTg, Vmt);
  convert_kernel<<<cdiv(BT_ * D_, 1024), 256, 0, stream>>>(x, srcb, BT_ * D_);

  for (int l = 0; l < 4; ++l) {
    convertL_kernel<<<13218, 256, 0, stream>>>(
        Wq + (size_t)l * 1048576, Wk + (size_t)l * 1048576, Wv + (size_t)l * 1048576,
        Wpk + (size_t)l * 1000000, Wpv + (size_t)l * 1000000,
        W1 + (size_t)l * 4194304, W2 + (size_t)l * 4194304,
        wqB, wpkB, wpvB, w1B, w2B);

    // Fused QKV (split epilogue): Q -> Qb, K^T -> KTg, V^T -> VTg
    gemm2p<0, false, false, true><<<dim3(24, 63, 1), 256, 0, stream>>>(
        srcb, wqB, Qb, nullptr, nullptr, nullptr, KTg, VTg,
        BT_, 3072, 1024, 1024, 1024, 1024, 0, 0, 0);

    // K position-mix + fused K-RoPE
    gemm2p<1, false, true, false><<<dim3(8, 8, 8), 256, 0, stream>>>(
        wpkB, KTg, Km, bpk + (size_t)l * 1000, cosT, sinT, nullptr, nullptr,
        1000, 1024, 1024, 1000, 1024, 1024, 0L, 1048576L, 1024000L);

    // V position-mix (transposed out)
    gemm2p<2, false, false, false><<<dim3(8, 8, 8), 256, 0, stream>>>(
        VTg, wpvB, Vmt, bpv + (size_t)l * 1000, nullptr, nullptr, nullptr, nullptr,
        1024, 1000, 1024, 1024, 1000, 1024, 1048576L, 0L, 1048576L);

    // Attention (Q-rope fused; K pre-roped), bf16 out
    attn_kernel<<<dim3(8, 64), 256, 0, stream>>>(Qb, Km, Vmt, yB, cosT, sinT);

    addln_kernel<false><<<BT_, 256, 0, stream>>>(srcb, yB, g1 + (size_t)l * 1024,
                                                 b1ln + (size_t)l * 1024, nullptr);

    // FFN1 (+bias+gelu) -> bf16 h
    gemm2p<2, true, false, false><<<dim3(32, 63, 1), 256, 0, stream>>>(
        srcb, w1B, hB, b1 + (size_t)l * 4096, nullptr, nullptr, nullptr, nullptr,
        BT_, 4096, 1024, 1024, 1024, 4096, 0, 0, 0);
    // FFN2 (+bias) -> bf16 yB
    gemm2p<2, false, false, false><<<dim3(8, 63, 1), 256, 0, stream>>>(
        hB, w2B, yB, b2 + (size_t)l * 1024, nullptr, nullptr, nullptr, nullptr,
        BT_, 1024, 4096, 4096, 4096, 1024, 0, 0, 0);

    if (l == 3) {
      addln_kernel<true><<<BT_, 256, 0, stream>>>(srcb, yB, g2 + (size_t)l * 1024,
                                                  b2ln + (size_t)l * 1024, (float*)d_out);
    } else {
      addln_kernel<false><<<BT_, 256, 0, stream>>>(srcb, yB, g2 + (size_t)l * 1024,
                                                   b2ln + (size_t)l * 1024, nullptr);
    }
  }
}

// Round 12
// 2028.572 us; speedup vs baseline: 1.2871x; 1.0000x over previous
//
#include <hip/hip_runtime.h>
#include <cstdint>
#include <cstddef>

// ---------------------------------------------------------------------------
// SelfAttentionTransformer on MI355X (gfx950).
// L=4, D=1024, H=8, HS=128, T=1000, DFF=4096, B=8.
// R12: attention QBLK=256 (8 waves x 32 q-rows, 512 thr) + XCD-aligned 1-D
//      grid (id%8 == bh%8 -> per-XCD K/V working set = 4MB = L2). Everything
//      else frozen at R11 (gemm2p plateau, bf16 residual, fused converts).
// ---------------------------------------------------------------------------

typedef unsigned short u16;
typedef unsigned int u32;
typedef __attribute__((ext_vector_type(8))) short s16x8;   // 8 bf16 raw bits
typedef __attribute__((ext_vector_type(4))) float f32x4;
typedef __attribute__((ext_vector_type(4))) unsigned short u16x4;

#define DEV static __device__ __forceinline__

DEV float bf2f(u16 u) { union { u32 u; float f; } v; v.u = ((u32)u) << 16; return v.f; }
DEV u16 f2bf(float f) {
  union { float f; u32 u; } v; v.f = f;
  return (u16)((v.u + 0x7fffu + ((v.u >> 16) & 1u)) >> 16);   // RNE
}

#define MFMA(acc_, a_, b_) \
  asm volatile("v_mfma_f32_16x16x32_bf16 %0, %1, %2, %0" : "+v"(acc_) : "v"(a_), "v"(b_))

#define GLD16(g_, l_) \
  __builtin_amdgcn_global_load_lds((const __attribute__((address_space(1))) void*)(g_), \
                                   (__attribute__((address_space(3))) void*)(l_), 16, 0, 0)

static constexpr int T_ = 1000, D_ = 1024, H_ = 8, HS_ = 128, B_ = 8;
static constexpr int BT_ = B_ * T_;   // 8000

// rope on 8 packed bf16 (4 pairs), table base i0 (pair index of element 0).
DEV void rope8(s16x8& v, const float* __restrict__ ct, const float* __restrict__ st,
               int t, int i0) {
  const f32x4 c4 = *(const f32x4*)(ct + t * 64 + i0);
  const f32x4 s4 = *(const f32x4*)(st + t * 64 + i0);
#pragma unroll
  for (int p = 0; p < 4; ++p) {
    const float xr = bf2f((u16)v[2 * p]), xi = bf2f((u16)v[2 * p + 1]);
    v[2 * p]     = (short)f2bf(xr * c4[p] - xi * s4[p]);
    v[2 * p + 1] = (short)f2bf(xr * s4[p] + xi * c4[p]);
  }
}

// ---------------------------------------------------------------------------
__global__ void tab_kernel(float* __restrict__ ct, float* __restrict__ st) {
  const int id = blockIdx.x * 256 + threadIdx.x;   // 64000
  const int i = id & 63, t = id >> 6;
  const float theta = powf(10000.f, -(float)i * (1.f / 64.f));
  const float ang = (float)t * theta;
  ct[id] = cosf(ang);
  st[id] = sinf(ang);
}

__global__ void convert_kernel(const float* __restrict__ in, u16* __restrict__ out, int n) {
  const int i = (blockIdx.x * 256 + threadIdx.x) * 4;
  if (i < n) {
    const float4 v = *(const float4*)(in + i);
    uint2 pk;
    pk.x = (u32)f2bf(v.x) | ((u32)f2bf(v.y) << 16);
    pk.y = (u32)f2bf(v.z) | ((u32)f2bf(v.w) << 16);
    *(uint2*)(out + i) = pk;
  }
}

// All 7 per-layer weight converts fused (float4 quads, segmented).
__global__ __launch_bounds__(256) void convertL_kernel(
    const float* __restrict__ Wq, const float* __restrict__ Wk, const float* __restrict__ Wv,
    const float* __restrict__ Wpk, const float* __restrict__ Wpv,
    const float* __restrict__ W1, const float* __restrict__ W2,
    u16* __restrict__ wq, u16* __restrict__ wpk, u16* __restrict__ wpv,
    u16* __restrict__ w1, u16* __restrict__ w2) {
  const int i = blockIdx.x * 256 + threadIdx.x;
  const float* src; u16* dst; int j;
  if      (i <  262144) { src = Wq;  dst = wq;            j = i; }
  else if (i <  524288) { src = Wk;  dst = wq + 1048576;  j = i -  262144; }
  else if (i <  786432) { src = Wv;  dst = wq + 2097152;  j = i -  524288; }
  else if (i < 1036432) { src = Wpk; dst = wpk;           j = i -  786432; }
  else if (i < 1286432) { src = Wpv; dst = wpv;           j = i - 1036432; }
  else if (i < 2335008) { src = W1;  dst = w1;            j = i - 1286432; }
  else if (i < 3383584) { src = W2;  dst = w2;            j = i - 2335008; }
  else return;
  const float4 v = ((const float4*)src)[j];
  uint2 pk;
  pk.x = (u32)f2bf(v.x) | ((u32)f2bf(v.y) << 16);
  pk.y = (u32)f2bf(v.z) | ((u32)f2bf(v.w) << 16);
  ((uint2*)dst)[j] = pk;
}

// Zero the t/u in [1000,1024) tails of KTg, VTg, Vmt ([8][1024][1024] each).
__global__ void zerotail_kernel(u16* __restrict__ KTg, u16* __restrict__ VTg,
                                u16* __restrict__ Vmt) {
  const int id = blockIdx.x * 256 + threadIdx.x;   // 3 * 8192 * 24 = 589824
  if (id >= 3 * 8192 * 24) return;
  const int which = id / 196608, rem = id % 196608;
  const int bd = rem / 24, t = 1000 + rem % 24;
  u16* p = (which == 0) ? KTg : (which == 1) ? VTg : Vmt;
  p[(size_t)bd * 1024 + t] = 0;
}

// ---------------------------------------------------------------------------
// gemm2p: proven 128x128 / BK=32 / 256-thread / double-buffered NT GEMM.
// RK: fuse K-RoPE into epilogue. SPLIT: QKV mode (Q | K^T | V^T outputs).
// ---------------------------------------------------------------------------
template <int BIAS, bool ACT, bool RK, bool SPLIT>   // BIAS: 0 none, 1 row, 2 col
__global__ __launch_bounds__(256) void gemm2p(
    const u16* __restrict__ A, const u16* __restrict__ B, u16* __restrict__ Cv,
    const float* __restrict__ bias, const float* __restrict__ ct,
    const float* __restrict__ st, u16* __restrict__ KT, u16* __restrict__ VT,
    int M, int N, int K, int lda, int ldb, int ldc, long sA, long sB, long sC) {
  __shared__ alignas(16) u16 As[2][4096];
  __shared__ alignas(16) u16 Bs[2][4096];
  const int z = blockIdx.z;
  A += (size_t)z * (size_t)sA;
  B += (size_t)z * (size_t)sB;
  const int m0 = blockIdx.y * 128, n0 = blockIdx.x * 128;
  const int tid = threadIdx.x;
  const int wid = tid >> 6, lane = tid & 63;
  const int wr = wid >> 1, wc = wid & 1;
  const int l15 = lane & 15, l4 = lane >> 4;
  const int srow = tid >> 2;
  const int sg = ((tid & 3) ^ ((tid >> 3) & 3)) << 3;
  const u16* gA0 = A + (size_t)min(m0 + srow, M - 1) * lda + sg;
  const u16* gA1 = A + (size_t)min(m0 + 64 + srow, M - 1) * lda + sg;
  const u16* gB0 = B + (size_t)min(n0 + srow, N - 1) * ldb + sg;
  const u16* gB1 = B + (size_t)min(n0 + 64 + srow, N - 1) * ldb + sg;
  const int gg = (l4 ^ ((l15 >> 1) & 3)) << 3;
  const int aBase = (wr * 64 + l15) * 32 + gg;
  const int bBase = (wc * 64 + l15) * 32 + gg;

  f32x4 acc[4][4] = {};
  const int KTn = K >> 5;
  GLD16(gA0, &As[0][tid * 8]);
  GLD16(gA1, &As[0][(256 + tid) * 8]);
  GLD16(gB0, &Bs[0][tid * 8]);
  GLD16(gB1, &Bs[0][(256 + tid) * 8]);
  __syncthreads();
  int cur = 0;
#pragma unroll 1
  for (int kt = 0; kt < KTn; ++kt) {
    if (kt + 1 < KTn) {
      const int kb = (kt + 1) << 5;
      GLD16(gA0 + kb, &As[cur ^ 1][tid * 8]);
      GLD16(gA1 + kb, &As[cur ^ 1][(256 + tid) * 8]);
      GLD16(gB0 + kb, &Bs[cur ^ 1][tid * 8]);
      GLD16(gB1 + kb, &Bs[cur ^ 1][(256 + tid) * 8]);
    }
    s16x8 af[4], bfr[4];
#pragma unroll
    for (int i = 0; i < 4; ++i) af[i] = *(const s16x8*)&As[cur][aBase + i * 512];
#pragma unroll
    for (int i = 0; i < 4; ++i) bfr[i] = *(const s16x8*)&Bs[cur][bBase + i * 512];
    __builtin_amdgcn_s_setprio(1);
#pragma unroll
    for (int mi = 0; mi < 4; ++mi)
#pragma unroll
      for (int ni = 0; ni < 4; ++ni) MFMA(acc[mi][ni], af[mi], bfr[ni]);
    __builtin_amdgcn_s_setprio(0);
    __syncthreads();
    cur ^= 1;
  }
  asm volatile("s_nop 7\n\ts_nop 7"
               : "+v"(acc[3][0]), "+v"(acc[3][1]), "+v"(acc[3][2]), "+v"(acc[3][3]));
  if constexpr (SPLIT) {
#pragma unroll
    for (int mi = 0; mi < 4; ++mi) {
      const int rb = m0 + wr * 64 + mi * 16 + l4 * 4;   // multiple of 4
      if (rb < M) {
#pragma unroll
        for (int ni = 0; ni < 4; ++ni) {
          const int colg = n0 + wc * 64 + ni * 16 + l15;
          if (colg < 1024) {
#pragma unroll
            for (int r = 0; r < 4; ++r)
              Cv[(size_t)(rb + r) * 1024 + colg] = f2bf(acc[mi][ni][r]);
          } else {
            u16* dst = (colg < 2048) ? KT : VT;
            const int dcol = colg & 1023;
            const int bq = rb / 1000;
            const int tq = rb - bq * 1000;   // mult of 4, <=996: no straddle
            u16x4 pk;
#pragma unroll
            for (int r = 0; r < 4; ++r) pk[r] = f2bf(acc[mi][ni][r]);
            *(u16x4*)(dst + (size_t)bq * 1048576 + (size_t)dcol * 1024 + tq) = pk;
          }
        }
      }
    }
  } else {
#pragma unroll
    for (int mi = 0; mi < 4; ++mi) {
#pragma unroll
      for (int ni = 0; ni < 4; ++ni) {
        const int colg = n0 + wc * 64 + ni * 16 + l15;
#pragma unroll
        for (int r = 0; r < 4; ++r) {
          const int rowg = m0 + wr * 64 + mi * 16 + l4 * 4 + r;
          float v = acc[mi][ni][r];
          if (BIAS == 1) v += bias[min(rowg, M - 1)];
          if (BIAS == 2) v += bias[min(colg, N - 1)];
          if constexpr (RK) {
            const int tt = min(rowg, T_ - 1);
            const int ii = (colg & 127) >> 1;
            const float c = ct[tt * 64 + ii], s = st[tt * 64 + ii];
            const float partner = __shfl_xor(v, 1);
            v = (colg & 1) ? (partner * s + v * c) : (v * c - partner * s);
          }
          if (ACT) v = 0.5f * v * (1.0f + erff(v * 0.70710678118654752f));
          if (rowg < M && colg < N)
            Cv[(size_t)z * (size_t)sC + (size_t)rowg * ldc + colg] = f2bf(v);
        }
      }
    }
  }
}

// ---------------------------------------------------------------------------
// Flash attention (non-causal), QBLK=256 (8 waves x 32 q-rows, 512 threads),
// KVBLK=64. 1-D grid id = qt*64 + bh so id%8 == bh%8 (XCD-local K/V; per-XCD
// working set 8 heads x 512KB = 4MB = L2). Per-wave math identical to R11.
// ---------------------------------------------------------------------------
__global__ __launch_bounds__(512) void attn_kernel(const u16* __restrict__ Q,
                                                   const u16* __restrict__ Km,
                                                   const u16* __restrict__ Vmt,
                                                   u16* __restrict__ Y,
                                                   const float* __restrict__ ct,
                                                   const float* __restrict__ st) {
  __shared__ alignas(16) u16 Ks[64][136];
  __shared__ alignas(16) u16 Vts[128][72];
  __shared__ alignas(16) u16 Ps[8][32][72];
  const int id = blockIdx.x;          // 256 = 4 qt x 64 bh
  const int bh = id & 63, qt = id >> 6;
  const int b = bh >> 3, h = bh & 7;
  const int tid = threadIdx.x;
  const int w = tid >> 6, lane = tid & 63;
  const int l15 = lane & 15, l4 = lane >> 4;
  const size_t qbase = (size_t)b * 1000 * 1024 + h * HS_;
  const size_t kbase = (size_t)b * 1024000 + h * HS_;
  const size_t vbase = (size_t)b * 1048576 + (size_t)(h * HS_) * 1024;
  const int q0 = qt * 256 + w * 32;
  s16x8 aq[2][4];
#pragma unroll
  for (int qf = 0; qf < 2; ++qf) {
    const int qrow = q0 + qf * 16 + l15;
#pragma unroll
    for (int c = 0; c < 4; ++c) {
      s16x8 v = {};
      if (qrow < T_) {
        v = *(const s16x8*)(Q + qbase + (size_t)qrow * 1024 + c * 32 + l4 * 8);
        rope8(v, ct, st, qrow, c * 16 + l4 * 4);
      }
      aq[qf][c] = v;
    }
  }
  s16x8 ones;
#pragma unroll
  for (int j = 0; j < 8; ++j) ones[j] = (short)0x3F80;   // bf16 1.0
  f32x4 acc[2][8] = {};
  f32x4 lsum[2] = {};
  float m_run[2][4];
#pragma unroll
  for (int qf = 0; qf < 2; ++qf)
#pragma unroll
    for (int r = 0; r < 4; ++r) m_run[qf][r] = -1e30f;
  const float SCALE = 0.08838834764831845f;
  for (int kt = 0; kt < 16; ++kt) {
    {  // stage K (64x128) and V^T (128x64) with 512 threads
      const int r = tid >> 3, c0 = (tid & 7) << 4;
      const int kk = kt * 64 + r;
#pragma unroll
      for (int v = 0; v < 2; ++v) {
        s16x8 val = {};
        if (kk < T_) val = *(const s16x8*)(Km + kbase + (size_t)kk * 1024 + c0 + v * 8);
        *(s16x8*)&Ks[r][c0 + v * 8] = val;
      }
      const int r2 = tid >> 2, cs = (tid & 3) << 4;
#pragma unroll
      for (int v = 0; v < 2; ++v) {
        const s16x8 val = *(const s16x8*)(Vmt + vbase + (size_t)r2 * 1024 + kt * 64 + cs + v * 8);
        *(s16x8*)&Vts[r2][cs + v * 8] = val;
      }
    }
    __syncthreads();
    f32x4 sacc[2][4] = {};
#pragma unroll
    for (int c = 0; c < 4; ++c) {
      s16x8 bk[4];
#pragma unroll
      for (int f = 0; f < 4; ++f) bk[f] = *(const s16x8*)&Ks[f * 16 + l15][c * 32 + l4 * 8];
#pragma unroll
      for (int qf = 0; qf < 2; ++qf)
#pragma unroll
        for (int f = 0; f < 4; ++f) MFMA(sacc[qf][f], aq[qf][c], bk[f]);
    }
    asm volatile("s_nop 7\n\ts_nop 7"
                 : "+v"(sacc[0][0]), "+v"(sacc[0][1]), "+v"(sacc[0][2]), "+v"(sacc[0][3]),
                   "+v"(sacc[1][0]), "+v"(sacc[1][1]), "+v"(sacc[1][2]), "+v"(sacc[1][3]));
#pragma unroll
    for (int qf = 0; qf < 2; ++qf) {
      float sv[4][4];
#pragma unroll
      for (int f = 0; f < 4; ++f) {
        const int key = kt * 64 + f * 16 + l15;
#pragma unroll
        for (int r = 0; r < 4; ++r) sv[f][r] = (key < T_) ? sacc[qf][f][r] * SCALE : -1e30f;
      }
#pragma unroll
      for (int r = 0; r < 4; ++r) {
        float mx = fmaxf(fmaxf(sv[0][r], sv[1][r]), fmaxf(sv[2][r], sv[3][r]));
#pragma unroll
        for (int off = 8; off >= 1; off >>= 1) mx = fmaxf(mx, __shfl_xor(mx, off));
        const float mn = fmaxf(m_run[qf][r], mx);
        const float corr = __expf(m_run[qf][r] - mn);
        m_run[qf][r] = mn;
#pragma unroll
        for (int f = 0; f < 4; ++f)
          Ps[w][qf * 16 + l4 * 4 + r][f * 16 + l15] = f2bf(__expf(sv[f][r] - mn));
        lsum[qf][r] *= corr;
#pragma unroll
        for (int n = 0; n < 8; ++n) acc[qf][n][r] *= corr;
      }
    }
    asm volatile("s_waitcnt lgkmcnt(0)" ::: "memory");   // own-wave Ps visible
    // O += P V ; lsum += P * ones (row-sum via MFMA)
#pragma unroll
    for (int c2 = 0; c2 < 2; ++c2) {
      s16x8 pa[2];
#pragma unroll
      for (int qf = 0; qf < 2; ++qf)
        pa[qf] = *(const s16x8*)&Ps[w][qf * 16 + l15][c2 * 32 + l4 * 8];
      MFMA(lsum[0], pa[0], ones);
      MFMA(lsum[1], pa[1], ones);
#pragma unroll
      for (int n = 0; n < 8; ++n) {
        const s16x8 vb = *(const s16x8*)&Vts[n * 16 + l15][c2 * 32 + l4 * 8];
#pragma unroll
        for (int qf = 0; qf < 2; ++qf) MFMA(acc[qf][n], pa[qf], vb);
      }
    }
    __syncthreads();
  }
  asm volatile("s_nop 7\n\ts_nop 7"
               : "+v"(acc[0][6]), "+v"(acc[0][7]), "+v"(acc[1][6]), "+v"(acc[1][7]),
                 "+v"(lsum[0]), "+v"(lsum[1]));
#pragma unroll
  for (int qf = 0; qf < 2; ++qf)
#pragma unroll
    for (int n = 0; n < 8; ++n)
#pragma unroll
      for (int r = 0; r < 4; ++r) {
        const int q = q0 + qf * 16 + l4 * 4 + r;
        if (q < T_)
          Y[(size_t)(b * 1000 + q) * 1024 + h * HS_ + n * 16 + l15] =
              f2bf(acc[qf][n][r] / lsum[qf][r]);
      }
}

// ---------------------------------------------------------------------------
// srcb = LN(srcb + add) * g + b   — bf16 residual master, fp32 math inside.
// FINAL: also write the fp32 result to outf (the harness output).
// ---------------------------------------------------------------------------
template <bool FINAL>
__global__ __launch_bounds__(256) void addln_kernel(u16* __restrict__ srcb,
                                                    const u16* __restrict__ add,
                                                    const float* __restrict__ g,
                                                    const float* __restrict__ bb,
                                                    float* __restrict__ outf) {
  const int row = blockIdx.x;
  const int tid = threadIdx.x;
  const int d = tid * 4;
  u16* s = srcb + (size_t)row * D_;
  const u16* a = add + (size_t)row * D_;
  const u16x4 sv = *(const u16x4*)(s + d);
  const u16x4 av = *(const u16x4*)(a + d);
  float x[4];
  float sum = 0.f, sq = 0.f;
#pragma unroll
  for (int i = 0; i < 4; ++i) {
    const float v = bf2f(sv[i]) + bf2f(av[i]);
    x[i] = v; sum += v; sq += v * v;
  }
#pragma unroll
  for (int off = 32; off >= 1; off >>= 1) { sum += __shfl_xor(sum, off); sq += __shfl_xor(sq, off); }
  __shared__ float red[8];
  const int wid = tid >> 6;
  if ((tid & 63) == 0) { red[wid] = sum; red[4 + wid] = sq; }
  __syncthreads();
  sum = red[0] + red[1] + red[2] + red[3];
  sq = red[4] + red[5] + red[6] + red[7];
  const float mean = sum * (1.f / 1024.f);
  const float var = sq * (1.f / 1024.f) - mean * mean;
  const float rstd = rsqrtf(var + 1e-5f);
  const f32x4 gv = *(const f32x4*)(g + d);
  const f32x4 bv = *(const f32x4*)(bb + d);
  f32x4 yv;
  u16x4 ob;
#pragma unroll
  for (int i = 0; i < 4; ++i) {
    const float y = (x[i] - mean) * rstd * gv[i] + bv[i];
    yv[i] = y;
    ob[i] = f2bf(y);
  }
  *(u16x4*)(s + d) = ob;
  if (FINAL) *(f32x4*)(outf + (size_t)row * D_ + d) = yv;
}

// ---------------------------------------------------------------------------
// Host orchestration
// ---------------------------------------------------------------------------
static inline int cdiv(int a, int b) { return (a + b - 1) / b; }

extern "C" void kernel_launch(void* const* d_in, const int* in_sizes, int n_in,
                              void* d_out, int out_size, void* d_ws, size_t ws_size,
                              hipStream_t stream) {
  const float* x    = (const float*)d_in[0];
  const float* Wq   = (const float*)d_in[1];
  const float* Wk   = (const float*)d_in[2];
  const float* Wv   = (const float*)d_in[3];
  const float* Wpk  = (const float*)d_in[4];
  const float* bpk  = (const float*)d_in[5];
  const float* Wpv  = (const float*)d_in[6];
  const float* bpv  = (const float*)d_in[7];
  const float* g1   = (const float*)d_in[8];
  const float* b1ln = (const float*)d_in[9];
  const float* W1   = (const float*)d_in[10];
  const float* b1   = (const float*)d_in[11];
  const float* W2   = (const float*)d_in[12];
  const float* b2   = (const float*)d_in[13];
  const float* g2   = (const float*)d_in[14];
  const float* b2ln = (const float*)d_in[15];

  char* wsb = (char*)d_ws;
  float* cosT = (float*)(wsb + 0);                //   256 KB
  float* sinT = (float*)(wsb + 262144);           //   256 KB
  u16* srcb   = (u16*)(wsb + 33292288);           // 16.38 MB bf16 residual master
  u16* Qb     = (u16*)(wsb + 49676288);           // 16.38 MB [8000][1024]
  u16* KTg    = (u16*)(wsb + 66060288);           // 16.78 MB [8][1024 d][1024 t]
  u16* VTg    = (u16*)(wsb + 82837504);           // 16.78 MB [8][1024 d][1024 t]
  u16* Km     = (u16*)(wsb + 99614720);           // 16.38 MB [8][1000][1024]
  u16* Vmt    = (u16*)(wsb + 115998720);          // 16.78 MB [8][1024 d][1024 u]
  u16* yB     = (u16*)(wsb + 132775936);          // 16.38 MB [8000][1024] bf16 y
  u16* wbuf   = (u16*)(wsb + 149159936);          // 27.07 MB layer weights
  u16* hB     = Qb;  // [8000][4096] overlaps Qb+KTg+VTg+Km (all dead at FFN time)

  u16* wqB  = wbuf + 0;          // [3072][1024] fused q,k,v
  u16* wpkB = wbuf + 3145728;    // [1000][1000]
  u16* wpvB = wbuf + 4145728;
  u16* w1B  = wbuf + 5145728;    // [4096][1024]
  u16* w2B  = wbuf + 9340032;    // [1024][4096]

  tab_kernel<<<250, 256, 0, stream>>>(cosT, sinT);
  zerotail_kernel<<<2304, 256, 0, stream>>>(KTg, VTg, Vmt);
  convert_kernel<<<cdiv(BT_ * D_, 1024), 256, 0, stream>>>(x, srcb, BT_ * D_);

  for (int l = 0; l < 4; ++l) {
    convertL_kernel<<<13218, 256, 0, stream>>>(
        Wq + (size_t)l * 1048576, Wk + (size_t)l * 1048576, Wv + (size_t)l * 1048576,
        Wpk + (size_t)l * 1000000, Wpv + (size_t)l * 1000000,
        W1 + (size_t)l * 4194304, W2 + (size_t)l * 4194304,
        wqB, wpkB, wpvB, w1B, w2B);

    // Fused QKV (split epilogue): Q -> Qb, K^T -> KTg, V^T -> VTg
    gemm2p<0, false, false, true><<<dim3(24, 63, 1), 256, 0, stream>>>(
        srcb, wqB, Qb, nullptr, nullptr, nullptr, KTg, VTg,
        BT_, 3072, 1024, 1024, 1024, 1024, 0, 0, 0);

    // K position-mix + fused K-RoPE
    gemm2p<1, false, true, false><<<dim3(8, 8, 8), 256, 0, stream>>>(
        wpkB, KTg, Km, bpk + (size_t)l * 1000, cosT, sinT, nullptr, nullptr,
        1000, 1024, 1024, 1000, 1024, 1024, 0L, 1048576L, 1024000L);

    // V position-mix (transposed out)
    gemm2p<2, false, false, false><<<dim3(8, 8, 8), 256, 0, stream>>>(
        VTg, wpvB, Vmt, bpv + (size_t)l * 1000, nullptr, nullptr, nullptr, nullptr,
        1024, 1000, 1024, 1024, 1000, 1024, 1048576L, 0L, 1048576L);

    // Attention: QBLK=256, 8 waves, XCD-aligned 1-D grid (id%8 == bh%8)
    attn_kernel<<<256, 512, 0, stream>>>(Qb, Km, Vmt, yB, cosT, sinT);

    addln_kernel<false><<<BT_, 256, 0, stream>>>(srcb, yB, g1 + (size_t)l * 1024,
                                                 b1ln + (size_t)l * 1024, nullptr);

    // FFN1 (+bias+gelu) -> bf16 h
    gemm2p<2, true, false, false><<<dim3(32, 63, 1), 256, 0, stream>>>(
        srcb, w1B, hB, b1 + (size_t)l * 4096, nullptr, nullptr, nullptr, nullptr,
        BT_, 4096, 1024, 1024, 1024, 4096, 0, 0, 0);
    // FFN2 (+bias) -> bf16 yB
    gemm2p<2, false, false, false><<<dim3(8, 63, 1), 256, 0, stream>>>(
        hB, w2B, yB, b2 + (size_t)l * 1024, nullptr, nullptr, nullptr, nullptr,
        BT_, 1024, 4096, 4096, 4096, 1024, 0, 0, 0);

    if (l == 3) {
      addln_kernel<true><<<BT_, 256, 0, stream>>>(srcb, yB, g2 + (size_t)l * 1024,
                                                  b2ln + (size_t)l * 1024, (float*)d_out);
    } else {
      addln_kernel<false><<<BT_, 256, 0, stream>>>(srcb, yB, g2 + (size_t)l * 1024,
                                                   b2ln + (size_t)l * 1024, nullptr);
    }
  }
}

// Round 13
// 1954.819 us; speedup vs baseline: 1.3357x; 1.0377x over previous
//
#include <hip/hip_runtime.h>
#include <cstdint>
#include <cstddef>

// ---------------------------------------------------------------------------
// SelfAttentionTransformer on MI355X (gfx950).
// L=4, D=1024, H=8, HS=128, T=1000, DFF=4096, B=8.
// R13: R12 + merged position-mix dispatch (K-mix+RoPE and V-mix in one
//      1024-block launch, grid z=16). Everything else frozen.
// ---------------------------------------------------------------------------

typedef unsigned short u16;
typedef unsigned int u32;
typedef __attribute__((ext_vector_type(8))) short s16x8;   // 8 bf16 raw bits
typedef __attribute__((ext_vector_type(4))) float f32x4;
typedef __attribute__((ext_vector_type(4))) unsigned short u16x4;

#define DEV static __device__ __forceinline__

DEV float bf2f(u16 u) { union { u32 u; float f; } v; v.u = ((u32)u) << 16; return v.f; }
DEV u16 f2bf(float f) {
  union { float f; u32 u; } v; v.f = f;
  return (u16)((v.u + 0x7fffu + ((v.u >> 16) & 1u)) >> 16);   // RNE
}

#define MFMA(acc_, a_, b_) \
  asm volatile("v_mfma_f32_16x16x32_bf16 %0, %1, %2, %0" : "+v"(acc_) : "v"(a_), "v"(b_))

#define GLD16(g_, l_) \
  __builtin_amdgcn_global_load_lds((const __attribute__((address_space(1))) void*)(g_), \
                                   (__attribute__((address_space(3))) void*)(l_), 16, 0, 0)

static constexpr int T_ = 1000, D_ = 1024, H_ = 8, HS_ = 128, B_ = 8;
static constexpr int BT_ = B_ * T_;   // 8000

// rope on 8 packed bf16 (4 pairs), table base i0 (pair index of element 0).
DEV void rope8(s16x8& v, const float* __restrict__ ct, const float* __restrict__ st,
               int t, int i0) {
  const f32x4 c4 = *(const f32x4*)(ct + t * 64 + i0);
  const f32x4 s4 = *(const f32x4*)(st + t * 64 + i0);
#pragma unroll
  for (int p = 0; p < 4; ++p) {
    const float xr = bf2f((u16)v[2 * p]), xi = bf2f((u16)v[2 * p + 1]);
    v[2 * p]     = (short)f2bf(xr * c4[p] - xi * s4[p]);
    v[2 * p + 1] = (short)f2bf(xr * s4[p] + xi * c4[p]);
  }
}

// ---------------------------------------------------------------------------
__global__ void tab_kernel(float* __restrict__ ct, float* __restrict__ st) {
  const int id = blockIdx.x * 256 + threadIdx.x;   // 64000
  const int i = id & 63, t = id >> 6;
  const float theta = powf(10000.f, -(float)i * (1.f / 64.f));
  const float ang = (float)t * theta;
  ct[id] = cosf(ang);
  st[id] = sinf(ang);
}

__global__ void convert_kernel(const float* __restrict__ in, u16* __restrict__ out, int n) {
  const int i = (blockIdx.x * 256 + threadIdx.x) * 4;
  if (i < n) {
    const float4 v = *(const float4*)(in + i);
    uint2 pk;
    pk.x = (u32)f2bf(v.x) | ((u32)f2bf(v.y) << 16);
    pk.y = (u32)f2bf(v.z) | ((u32)f2bf(v.w) << 16);
    *(uint2*)(out + i) = pk;
  }
}

// All 7 per-layer weight converts fused (float4 quads, segmented).
__global__ __launch_bounds__(256) void convertL_kernel(
    const float* __restrict__ Wq, const float* __restrict__ Wk, const float* __restrict__ Wv,
    const float* __restrict__ Wpk, const float* __restrict__ Wpv,
    const float* __restrict__ W1, const float* __restrict__ W2,
    u16* __restrict__ wq, u16* __restrict__ wpk, u16* __restrict__ wpv,
    u16* __restrict__ w1, u16* __restrict__ w2) {
  const int i = blockIdx.x * 256 + threadIdx.x;
  const float* src; u16* dst; int j;
  if      (i <  262144) { src = Wq;  dst = wq;            j = i; }
  else if (i <  524288) { src = Wk;  dst = wq + 1048576;  j = i -  262144; }
  else if (i <  786432) { src = Wv;  dst = wq + 2097152;  j = i -  524288; }
  else if (i < 1036432) { src = Wpk; dst = wpk;           j = i -  786432; }
  else if (i < 1286432) { src = Wpv; dst = wpv;           j = i - 1036432; }
  else if (i < 2335008) { src = W1;  dst = w1;            j = i - 1286432; }
  else if (i < 3383584) { src = W2;  dst = w2;            j = i - 2335008; }
  else return;
  const float4 v = ((const float4*)src)[j];
  uint2 pk;
  pk.x = (u32)f2bf(v.x) | ((u32)f2bf(v.y) << 16);
  pk.y = (u32)f2bf(v.z) | ((u32)f2bf(v.w) << 16);
  ((uint2*)dst)[j] = pk;
}

// Zero the t/u in [1000,1024) tails of KTg, VTg, Vmt ([8][1024][1024] each).
__global__ void zerotail_kernel(u16* __restrict__ KTg, u16* __restrict__ VTg,
                                u16* __restrict__ Vmt) {
  const int id = blockIdx.x * 256 + threadIdx.x;   // 3 * 8192 * 24 = 589824
  if (id >= 3 * 8192 * 24) return;
  const int which = id / 196608, rem = id % 196608;
  const int bd = rem / 24, t = 1000 + rem % 24;
  u16* p = (which == 0) ? KTg : (which == 1) ? VTg : Vmt;
  p[(size_t)bd * 1024 + t] = 0;
}

// ---------------------------------------------------------------------------
// gemm2p: proven 128x128 / BK=32 / 256-thread / double-buffered NT GEMM.
// SPLIT: QKV mode (Q | K^T | V^T outputs).
// ---------------------------------------------------------------------------
template <int BIAS, bool ACT, bool SPLIT>   // BIAS: 0 none, 2 col
__global__ __launch_bounds__(256) void gemm2p(
    const u16* __restrict__ A, const u16* __restrict__ B, u16* __restrict__ Cv,
    const float* __restrict__ bias, u16* __restrict__ KT, u16* __restrict__ VT,
    int M, int N, int K, int lda, int ldb, int ldc, long sA, long sB, long sC) {
  __shared__ alignas(16) u16 As[2][4096];
  __shared__ alignas(16) u16 Bs[2][4096];
  const int z = blockIdx.z;
  A += (size_t)z * (size_t)sA;
  B += (size_t)z * (size_t)sB;
  const int m0 = blockIdx.y * 128, n0 = blockIdx.x * 128;
  const int tid = threadIdx.x;
  const int wid = tid >> 6, lane = tid & 63;
  const int wr = wid >> 1, wc = wid & 1;
  const int l15 = lane & 15, l4 = lane >> 4;
  const int srow = tid >> 2;
  const int sg = ((tid & 3) ^ ((tid >> 3) & 3)) << 3;
  const u16* gA0 = A + (size_t)min(m0 + srow, M - 1) * lda + sg;
  const u16* gA1 = A + (size_t)min(m0 + 64 + srow, M - 1) * lda + sg;
  const u16* gB0 = B + (size_t)min(n0 + srow, N - 1) * ldb + sg;
  const u16* gB1 = B + (size_t)min(n0 + 64 + srow, N - 1) * ldb + sg;
  const int gg = (l4 ^ ((l15 >> 1) & 3)) << 3;
  const int aBase = (wr * 64 + l15) * 32 + gg;
  const int bBase = (wc * 64 + l15) * 32 + gg;

  f32x4 acc[4][4] = {};
  const int KTn = K >> 5;
  GLD16(gA0, &As[0][tid * 8]);
  GLD16(gA1, &As[0][(256 + tid) * 8]);
  GLD16(gB0, &Bs[0][tid * 8]);
  GLD16(gB1, &Bs[0][(256 + tid) * 8]);
  __syncthreads();
  int cur = 0;
#pragma unroll 1
  for (int kt = 0; kt < KTn; ++kt) {
    if (kt + 1 < KTn) {
      const int kb = (kt + 1) << 5;
      GLD16(gA0 + kb, &As[cur ^ 1][tid * 8]);
      GLD16(gA1 + kb, &As[cur ^ 1][(256 + tid) * 8]);
      GLD16(gB0 + kb, &Bs[cur ^ 1][tid * 8]);
      GLD16(gB1 + kb, &Bs[cur ^ 1][(256 + tid) * 8]);
    }
    s16x8 af[4], bfr[4];
#pragma unroll
    for (int i = 0; i < 4; ++i) af[i] = *(const s16x8*)&As[cur][aBase + i * 512];
#pragma unroll
    for (int i = 0; i < 4; ++i) bfr[i] = *(const s16x8*)&Bs[cur][bBase + i * 512];
    __builtin_amdgcn_s_setprio(1);
#pragma unroll
    for (int mi = 0; mi < 4; ++mi)
#pragma unroll
      for (int ni = 0; ni < 4; ++ni) MFMA(acc[mi][ni], af[mi], bfr[ni]);
    __builtin_amdgcn_s_setprio(0);
    __syncthreads();
    cur ^= 1;
  }
  asm volatile("s_nop 7\n\ts_nop 7"
               : "+v"(acc[3][0]), "+v"(acc[3][1]), "+v"(acc[3][2]), "+v"(acc[3][3]));
  if constexpr (SPLIT) {
#pragma unroll
    for (int mi = 0; mi < 4; ++mi) {
      const int rb = m0 + wr * 64 + mi * 16 + l4 * 4;   // multiple of 4
      if (rb < M) {
#pragma unroll
        for (int ni = 0; ni < 4; ++ni) {
          const int colg = n0 + wc * 64 + ni * 16 + l15;
          if (colg < 1024) {
#pragma unroll
            for (int r = 0; r < 4; ++r)
              Cv[(size_t)(rb + r) * 1024 + colg] = f2bf(acc[mi][ni][r]);
          } else {
            u16* dst = (colg < 2048) ? KT : VT;
            const int dcol = colg & 1023;
            const int bq = rb / 1000;
            const int tq = rb - bq * 1000;   // mult of 4, <=996: no straddle
            u16x4 pk;
#pragma unroll
            for (int r = 0; r < 4; ++r) pk[r] = f2bf(acc[mi][ni][r]);
            *(u16x4*)(dst + (size_t)bq * 1048576 + (size_t)dcol * 1024 + tq) = pk;
          }
        }
      }
    }
  } else {
#pragma unroll
    for (int mi = 0; mi < 4; ++mi) {
#pragma unroll
      for (int ni = 0; ni < 4; ++ni) {
        const int colg = n0 + wc * 64 + ni * 16 + l15;
#pragma unroll
        for (int r = 0; r < 4; ++r) {
          const int rowg = m0 + wr * 64 + mi * 16 + l4 * 4 + r;
          float v = acc[mi][ni][r];
          if (BIAS == 2) v += bias[min(colg, N - 1)];
          if (ACT) v = 0.5f * v * (1.0f + erff(v * 0.70710678118654752f));
          if (rowg < M && colg < N)
            Cv[(size_t)z * (size_t)sC + (size_t)rowg * ldc + colg] = f2bf(v);
        }
      }
    }
  }
}

// ---------------------------------------------------------------------------
// gemm_mix: both position-mix GEMMs in ONE dispatch. grid (8, 8, 16).
//  z <  8 (K-mix): Km[z][u][d] = rope(sum_t Wpk[u,t]*KTg[z][d][t] + bpk[u])
//  z >= 8 (V-mix): Vmt[z][d][u] = sum_t VTg[z][d][t]*Wpv[u,t] + bpv[u]
// Same proven 128x128 / BK=32 main loop; runtime (block-uniform) mode branch.
// ---------------------------------------------------------------------------
__global__ __launch_bounds__(256) void gemm_mix(
    const u16* __restrict__ wpk, const u16* __restrict__ KTg, u16* __restrict__ Km,
    const float* __restrict__ bpk,
    const u16* __restrict__ VTg, const u16* __restrict__ wpv, u16* __restrict__ Vmt,
    const float* __restrict__ bpv,
    const float* __restrict__ ct, const float* __restrict__ st) {
  __shared__ alignas(16) u16 As[2][4096];
  __shared__ alignas(16) u16 Bs[2][4096];
  const bool isK = blockIdx.z < 8;
  const int zz = blockIdx.z & 7;
  const u16* A = isK ? wpk : VTg + (size_t)zz * 1048576;
  const u16* B = isK ? KTg + (size_t)zz * 1048576 : wpv;
  const int M = isK ? 1000 : 1024, N = isK ? 1024 : 1000;
  const int lda = isK ? 1000 : 1024, ldb = isK ? 1024 : 1000;
  const int m0 = blockIdx.y * 128, n0 = blockIdx.x * 128;
  const int tid = threadIdx.x;
  const int wid = tid >> 6, lane = tid & 63;
  const int wr = wid >> 1, wc = wid & 1;
  const int l15 = lane & 15, l4 = lane >> 4;
  const int srow = tid >> 2;
  const int sg = ((tid & 3) ^ ((tid >> 3) & 3)) << 3;
  const u16* gA0 = A + (size_t)min(m0 + srow, M - 1) * lda + sg;
  const u16* gA1 = A + (size_t)min(m0 + 64 + srow, M - 1) * lda + sg;
  const u16* gB0 = B + (size_t)min(n0 + srow, N - 1) * ldb + sg;
  const u16* gB1 = B + (size_t)min(n0 + 64 + srow, N - 1) * ldb + sg;
  const int gg = (l4 ^ ((l15 >> 1) & 3)) << 3;
  const int aBase = (wr * 64 + l15) * 32 + gg;
  const int bBase = (wc * 64 + l15) * 32 + gg;

  f32x4 acc[4][4] = {};
  GLD16(gA0, &As[0][tid * 8]);
  GLD16(gA1, &As[0][(256 + tid) * 8]);
  GLD16(gB0, &Bs[0][tid * 8]);
  GLD16(gB1, &Bs[0][(256 + tid) * 8]);
  __syncthreads();
  int cur = 0;
#pragma unroll 1
  for (int kt = 0; kt < 32; ++kt) {
    if (kt + 1 < 32) {
      const int kb = (kt + 1) << 5;
      GLD16(gA0 + kb, &As[cur ^ 1][tid * 8]);
      GLD16(gA1 + kb, &As[cur ^ 1][(256 + tid) * 8]);
      GLD16(gB0 + kb, &Bs[cur ^ 1][tid * 8]);
      GLD16(gB1 + kb, &Bs[cur ^ 1][(256 + tid) * 8]);
    }
    s16x8 af[4], bfr[4];
#pragma unroll
    for (int i = 0; i < 4; ++i) af[i] = *(const s16x8*)&As[cur][aBase + i * 512];
#pragma unroll
    for (int i = 0; i < 4; ++i) bfr[i] = *(const s16x8*)&Bs[cur][bBase + i * 512];
    __builtin_amdgcn_s_setprio(1);
#pragma unroll
    for (int mi = 0; mi < 4; ++mi)
#pragma unroll
      for (int ni = 0; ni < 4; ++ni) MFMA(acc[mi][ni], af[mi], bfr[ni]);
    __builtin_amdgcn_s_setprio(0);
    __syncthreads();
    cur ^= 1;
  }
  asm volatile("s_nop 7\n\ts_nop 7"
               : "+v"(acc[3][0]), "+v"(acc[3][1]), "+v"(acc[3][2]), "+v"(acc[3][3]));
#pragma unroll
  for (int mi = 0; mi < 4; ++mi) {
#pragma unroll
    for (int ni = 0; ni < 4; ++ni) {
      const int colg = n0 + wc * 64 + ni * 16 + l15;
#pragma unroll
      for (int r = 0; r < 4; ++r) {
        const int rowg = m0 + wr * 64 + mi * 16 + l4 * 4 + r;
        float v = acc[mi][ni][r];
        if (isK) {
          v += bpk[min(rowg, 999)];
          const int tt = min(rowg, 999);
          const int ii = (colg & 127) >> 1;
          const float c = ct[tt * 64 + ii], s = st[tt * 64 + ii];
          const float partner = __shfl_xor(v, 1);
          v = (colg & 1) ? (partner * s + v * c) : (v * c - partner * s);
          if (rowg < 1000)
            Km[(size_t)zz * 1024000 + (size_t)rowg * 1024 + colg] = f2bf(v);
        } else {
          v += bpv[min(colg, 999)];
          if (colg < 1000)
            Vmt[(size_t)zz * 1048576 + (size_t)rowg * 1024 + colg] = f2bf(v);
        }
      }
    }
  }
}

// ---------------------------------------------------------------------------
// Flash attention (non-causal), QBLK=256 (8 waves x 32 q-rows, 512 threads),
// KVBLK=64. 1-D grid id = qt*64 + bh (XCD-local K/V).
// ---------------------------------------------------------------------------
__global__ __launch_bounds__(512) void attn_kernel(const u16* __restrict__ Q,
                                                   const u16* __restrict__ Km,
                                                   const u16* __restrict__ Vmt,
                                                   u16* __restrict__ Y,
                                                   const float* __restrict__ ct,
                                                   const float* __restrict__ st) {
  __shared__ alignas(16) u16 Ks[64][136];
  __shared__ alignas(16) u16 Vts[128][72];
  __shared__ alignas(16) u16 Ps[8][32][72];
  const int id = blockIdx.x;          // 256 = 4 qt x 64 bh
  const int bh = id & 63, qt = id >> 6;
  const int b = bh >> 3, h = bh & 7;
  const int tid = threadIdx.x;
  const int w = tid >> 6, lane = tid & 63;
  const int l15 = lane & 15, l4 = lane >> 4;
  const size_t qbase = (size_t)b * 1000 * 1024 + h * HS_;
  const size_t kbase = (size_t)b * 1024000 + h * HS_;
  const size_t vbase = (size_t)b * 1048576 + (size_t)(h * HS_) * 1024;
  const int q0 = qt * 256 + w * 32;
  s16x8 aq[2][4];
#pragma unroll
  for (int qf = 0; qf < 2; ++qf) {
    const int qrow = q0 + qf * 16 + l15;
#pragma unroll
    for (int c = 0; c < 4; ++c) {
      s16x8 v = {};
      if (qrow < T_) {
        v = *(const s16x8*)(Q + qbase + (size_t)qrow * 1024 + c * 32 + l4 * 8);
        rope8(v, ct, st, qrow, c * 16 + l4 * 4);
      }
      aq[qf][c] = v;
    }
  }
  s16x8 ones;
#pragma unroll
  for (int j = 0; j < 8; ++j) ones[j] = (short)0x3F80;   // bf16 1.0
  f32x4 acc[2][8] = {};
  f32x4 lsum[2] = {};
  float m_run[2][4];
#pragma unroll
  for (int qf = 0; qf < 2; ++qf)
#pragma unroll
    for (int r = 0; r < 4; ++r) m_run[qf][r] = -1e30f;
  const float SCALE = 0.08838834764831845f;
  for (int kt = 0; kt < 16; ++kt) {
    {  // stage K (64x128) and V^T (128x64) with 512 threads
      const int r = tid >> 3, c0 = (tid & 7) << 4;
      const int kk = kt * 64 + r;
#pragma unroll
      for (int v = 0; v < 2; ++v) {
        s16x8 val = {};
        if (kk < T_) val = *(const s16x8*)(Km + kbase + (size_t)kk * 1024 + c0 + v * 8);
        *(s16x8*)&Ks[r][c0 + v * 8] = val;
      }
      const int r2 = tid >> 2, cs = (tid & 3) << 4;
#pragma unroll
      for (int v = 0; v < 2; ++v) {
        const s16x8 val = *(const s16x8*)(Vmt + vbase + (size_t)r2 * 1024 + kt * 64 + cs + v * 8);
        *(s16x8*)&Vts[r2][cs + v * 8] = val;
      }
    }
    __syncthreads();
    f32x4 sacc[2][4] = {};
#pragma unroll
    for (int c = 0; c < 4; ++c) {
      s16x8 bk[4];
#pragma unroll
      for (int f = 0; f < 4; ++f) bk[f] = *(const s16x8*)&Ks[f * 16 + l15][c * 32 + l4 * 8];
#pragma unroll
      for (int qf = 0; qf < 2; ++qf)
#pragma unroll
        for (int f = 0; f < 4; ++f) MFMA(sacc[qf][f], aq[qf][c], bk[f]);
    }
    asm volatile("s_nop 7\n\ts_nop 7"
                 : "+v"(sacc[0][0]), "+v"(sacc[0][1]), "+v"(sacc[0][2]), "+v"(sacc[0][3]),
                   "+v"(sacc[1][0]), "+v"(sacc[1][1]), "+v"(sacc[1][2]), "+v"(sacc[1][3]));
#pragma unroll
    for (int qf = 0; qf < 2; ++qf) {
      float sv[4][4];
#pragma unroll
      for (int f = 0; f < 4; ++f) {
        const int key = kt * 64 + f * 16 + l15;
#pragma unroll
        for (int r = 0; r < 4; ++r) sv[f][r] = (key < T_) ? sacc[qf][f][r] * SCALE : -1e30f;
      }
#pragma unroll
      for (int r = 0; r < 4; ++r) {
        float mx = fmaxf(fmaxf(sv[0][r], sv[1][r]), fmaxf(sv[2][r], sv[3][r]));
#pragma unroll
        for (int off = 8; off >= 1; off >>= 1) mx = fmaxf(mx, __shfl_xor(mx, off));
        const float mn = fmaxf(m_run[qf][r], mx);
        const float corr = __expf(m_run[qf][r] - mn);
        m_run[qf][r] = mn;
#pragma unroll
        for (int f = 0; f < 4; ++f)
          Ps[w][qf * 16 + l4 * 4 + r][f * 16 + l15] = f2bf(__expf(sv[f][r] - mn));
        lsum[qf][r] *= corr;
#pragma unroll
        for (int n = 0; n < 8; ++n) acc[qf][n][r] *= corr;
      }
    }
    asm volatile("s_waitcnt lgkmcnt(0)" ::: "memory");   // own-wave Ps visible
#pragma unroll
    for (int c2 = 0; c2 < 2; ++c2) {
      s16x8 pa[2];
#pragma unroll
      for (int qf = 0; qf < 2; ++qf)
        pa[qf] = *(const s16x8*)&Ps[w][qf * 16 + l15][c2 * 32 + l4 * 8];
      MFMA(lsum[0], pa[0], ones);
      MFMA(lsum[1], pa[1], ones);
#pragma unroll
      for (int n = 0; n < 8; ++n) {
        const s16x8 vb = *(const s16x8*)&Vts[n * 16 + l15][c2 * 32 + l4 * 8];
#pragma unroll
        for (int qf = 0; qf < 2; ++qf) MFMA(acc[qf][n], pa[qf], vb);
      }
    }
    __syncthreads();
  }
  asm volatile("s_nop 7\n\ts_nop 7"
               : "+v"(acc[0][6]), "+v"(acc[0][7]), "+v"(acc[1][6]), "+v"(acc[1][7]),
                 "+v"(lsum[0]), "+v"(lsum[1]));
#pragma unroll
  for (int qf = 0; qf < 2; ++qf)
#pragma unroll
    for (int n = 0; n < 8; ++n)
#pragma unroll
      for (int r = 0; r < 4; ++r) {
        const int q = q0 + qf * 16 + l4 * 4 + r;
        if (q < T_)
          Y[(size_t)(b * 1000 + q) * 1024 + h * HS_ + n * 16 + l15] =
              f2bf(acc[qf][n][r] / lsum[qf][r]);
      }
}

// ---------------------------------------------------------------------------
// srcb = LN(srcb + add) * g + b   — bf16 residual master, fp32 math inside.
// FINAL: also write the fp32 result to outf (the harness output).
// ---------------------------------------------------------------------------
template <bool FINAL>
__global__ __launch_bounds__(256) void addln_kernel(u16* __restrict__ srcb,
                                                    const u16* __restrict__ add,
                                                    const float* __restrict__ g,
                                                    const float* __restrict__ bb,
                                                    float* __restrict__ outf) {
  const int row = blockIdx.x;
  const int tid = threadIdx.x;
  const int d = tid * 4;
  u16* s = srcb + (size_t)row * D_;
  const u16* a = add + (size_t)row * D_;
  const u16x4 sv = *(const u16x4*)(s + d);
  const u16x4 av = *(const u16x4*)(a + d);
  float x[4];
  float sum = 0.f, sq = 0.f;
#pragma unroll
  for (int i = 0; i < 4; ++i) {
    const float v = bf2f(sv[i]) + bf2f(av[i]);
    x[i] = v; sum += v; sq += v * v;
  }
#pragma unroll
  for (int off = 32; off >= 1; off >>= 1) { sum += __shfl_xor(sum, off); sq += __shfl_xor(sq, off); }
  __shared__ float red[8];
  const int wid = tid >> 6;
  if ((tid & 63) == 0) { red[wid] = sum; red[4 + wid] = sq; }
  __syncthreads();
  sum = red[0] + red[1] + red[2] + red[3];
  sq = red[4] + red[5] + red[6] + red[7];
  const float mean = sum * (1.f / 1024.f);
  const float var = sq * (1.f / 1024.f) - mean * mean;
  const float rstd = rsqrtf(var + 1e-5f);
  const f32x4 gv = *(const f32x4*)(g + d);
  const f32x4 bv = *(const f32x4*)(bb + d);
  f32x4 yv;
  u16x4 ob;
#pragma unroll
  for (int i = 0; i < 4; ++i) {
    const float y = (x[i] - mean) * rstd * gv[i] + bv[i];
    yv[i] = y;
    ob[i] = f2bf(y);
  }
  *(u16x4*)(s + d) = ob;
  if (FINAL) *(f32x4*)(outf + (size_t)row * D_ + d) = yv;
}

// ---------------------------------------------------------------------------
// Host orchestration
// ---------------------------------------------------------------------------
static inline int cdiv(int a, int b) { return (a + b - 1) / b; }

extern "C" void kernel_launch(void* const* d_in, const int* in_sizes, int n_in,
                              void* d_out, int out_size, void* d_ws, size_t ws_size,
                              hipStream_t stream) {
  const float* x    = (const float*)d_in[0];
  const float* Wq   = (const float*)d_in[1];
  const float* Wk   = (const float*)d_in[2];
  const float* Wv   = (const float*)d_in[3];
  const float* Wpk  = (const float*)d_in[4];
  const float* bpk  = (const float*)d_in[5];
  const float* Wpv  = (const float*)d_in[6];
  const float* bpv  = (const float*)d_in[7];
  const float* g1   = (const float*)d_in[8];
  const float* b1ln = (const float*)d_in[9];
  const float* W1   = (const float*)d_in[10];
  const float* b1   = (const float*)d_in[11];
  const float* W2   = (const float*)d_in[12];
  const float* b2   = (const float*)d_in[13];
  const float* g2   = (const float*)d_in[14];
  const float* b2ln = (const float*)d_in[15];

  char* wsb = (char*)d_ws;
  float* cosT = (float*)(wsb + 0);                //   256 KB
  float* sinT = (float*)(wsb + 262144);           //   256 KB
  u16* srcb   = (u16*)(wsb + 33292288);           // 16.38 MB bf16 residual master
  u16* Qb     = (u16*)(wsb + 49676288);           // 16.38 MB [8000][1024]
  u16* KTg    = (u16*)(wsb + 66060288);           // 16.78 MB [8][1024 d][1024 t]
  u16* VTg    = (u16*)(wsb + 82837504);           // 16.78 MB [8][1024 d][1024 t]
  u16* Km     = (u16*)(wsb + 99614720);           // 16.38 MB [8][1000][1024]
  u16* Vmt    = (u16*)(wsb + 115998720);          // 16.78 MB [8][1024 d][1024 u]
  u16* yB     = (u16*)(wsb + 132775936);          // 16.38 MB [8000][1024] bf16 y
  u16* wbuf   = (u16*)(wsb + 149159936);          // 27.07 MB layer weights
  u16* hB     = Qb;  // [8000][4096] overlaps Qb+KTg+VTg+Km (all dead at FFN time)

  u16* wqB  = wbuf + 0;          // [3072][1024] fused q,k,v
  u16* wpkB = wbuf + 3145728;    // [1000][1000]
  u16* wpvB = wbuf + 4145728;
  u16* w1B  = wbuf + 5145728;    // [4096][1024]
  u16* w2B  = wbuf + 9340032;    // [1024][4096]

  tab_kernel<<<250, 256, 0, stream>>>(cosT, sinT);
  zerotail_kernel<<<2304, 256, 0, stream>>>(KTg, VTg, Vmt);
  convert_kernel<<<cdiv(BT_ * D_, 1024), 256, 0, stream>>>(x, srcb, BT_ * D_);

  for (int l = 0; l < 4; ++l) {
    convertL_kernel<<<13218, 256, 0, stream>>>(
        Wq + (size_t)l * 1048576, Wk + (size_t)l * 1048576, Wv + (size_t)l * 1048576,
        Wpk + (size_t)l * 1000000, Wpv + (size_t)l * 1000000,
        W1 + (size_t)l * 4194304, W2 + (size_t)l * 4194304,
        wqB, wpkB, wpvB, w1B, w2B);

    // Fused QKV (split epilogue): Q -> Qb, K^T -> KTg, V^T -> VTg
    gemm2p<0, false, true><<<dim3(24, 63, 1), 256, 0, stream>>>(
        srcb, wqB, Qb, nullptr, KTg, VTg,
        BT_, 3072, 1024, 1024, 1024, 1024, 0, 0, 0);

    // Merged position-mix: z<8 K-mix(+RoPE), z>=8 V-mix (one 1024-block launch)
    gemm_mix<<<dim3(8, 8, 16), 256, 0, stream>>>(
        wpkB, KTg, Km, bpk + (size_t)l * 1000,
        VTg, wpvB, Vmt, bpv + (size_t)l * 1000, cosT, sinT);

    // Attention: QBLK=256, 8 waves, XCD-aligned 1-D grid
    attn_kernel<<<256, 512, 0, stream>>>(Qb, Km, Vmt, yB, cosT, sinT);

    addln_kernel<false><<<BT_, 256, 0, stream>>>(srcb, yB, g1 + (size_t)l * 1024,
                                                 b1ln + (size_t)l * 1024, nullptr);

    // FFN1 (+bias+gelu) -> bf16 h
    gemm2p<2, true, false><<<dim3(32, 63, 1), 256, 0, stream>>>(
        srcb, w1B, hB, b1 + (size_t)l * 4096, nullptr, nullptr,
        BT_, 4096, 1024, 1024, 1024, 4096, 0, 0, 0);
    // FFN2 (+bias) -> bf16 yB
    gemm2p<2, false, false><<<dim3(8, 63, 1), 256, 0, stream>>>(
        hB, w2B, yB, b2 + (size_t)l * 1024, nullptr, nullptr,
        BT_, 1024, 4096, 4096, 4096, 1024, 0, 0, 0);

    if (l == 3) {
      addln_kernel<true><<<BT_, 256, 0, stream>>>(srcb, yB, g2 + (size_t)l * 1024,
                                                  b2ln + (size_t)l * 1024, (float*)d_out);
    } else {
      addln_kernel<false><<<BT_, 256, 0, stream>>>(srcb, yB, g2 + (size_t)l * 1024,
                                                   b2ln + (size_t)l * 1024, nullptr);
    }
  }
}